// Round 3
// baseline (2455.476 us; speedup 1.0000x reference)
//
#include <hip/hip_runtime.h>

// GCN: 3x (GEMM 128x128 + normalized scatter-sum) + mean-pool + linear + softmax.
// R1: two-stage pool. R2: parallel scan. R3: bf16 + split-W MFMA GEMM.
// R4: agg multi-edge-in-flight; h pre-scaled by dinv. R5: CSR via two-level bucket sort.
// R6 FAILED (fusion cut gather parallelism). R7/R8: 16/32 edges in flight (neutral ->
// agg not ILP-bound). R9: fp8 e4m3 gather payload (292us).
// R10 FAILED (cooperative 10x grid.sync flushed per-XCD L2s: 505MB HBM/dispatch).
// R11: gemm 128-row blocks (2:1 MFMA:W-load), pool uint4, scatter 4096-chunks (277us).
// R12: bucket-major agg: one block per 128-node bucket, 64KB LDS f32 acc, stream
//      unsorted slab (each edge touched once - kills the 32-slot/deg-17 masked-load
//      waste), ds_add_f32 accumulate, fused coalesced epilogue. k_fine's sort +
//      src16 roundtrip replaced by trivial k_degree. gbuf8 bytes feat-permuted
//      (byte 8f+k = feat f+16k) so LDS atomics spread 16 banks instead of 4.
// Assumes n <= 65536 (packed u16 src), n <= 512*128, bucket load < CAP (8.5 sigma).

#define NF 128
#define MAXBUCK 512
#define CAP 2560           // slab capacity per bucket (mean 2176, sigma ~45)
#define L1_CHUNK 4096
#define L1_THREADS 512
#define L1_PER_THREAD 8    // L1_CHUNK / L1_THREADS
#define PPG 8              // pool partials per graph
#define AGT 512            // agg threads

typedef __attribute__((ext_vector_type(8))) short short8;
typedef __attribute__((ext_vector_type(4))) float floatx4;
typedef __attribute__((ext_vector_type(2))) float floatx2;

__device__ __forceinline__ unsigned int bf16_rne(float x) {
    unsigned int u = __float_as_uint(x);
    return (u + 0x7fffu + ((u >> 16) & 1u)) >> 16;
}
__device__ __forceinline__ unsigned int pack_bf16_rne(float x, float y) {
    return bf16_rne(x) | (bf16_rne(y) << 16);
}
__device__ __forceinline__ float bf16u_to_f32(unsigned int u) {
    return __uint_as_float(u << 16);
}

// ---- repack all 3 W (fp32 [k][n]) into B-fragment-major bf16 hi/lo.
// Block 0 also zeroes the bucket cursors — runs before scatter. ----
__global__ __launch_bounds__(256) void k_repack_w3(const float* __restrict__ W0,
                                                   const float* __restrict__ W1,
                                                   const float* __restrict__ W2,
                                                   unsigned short* __restrict__ whi,
                                                   unsigned short* __restrict__ wlo,
                                                   int* __restrict__ bucket_cursor) {
    if (blockIdx.x == 0) {
        for (int i = threadIdx.x; i <= MAXBUCK; i += 256) bucket_cursor[i] = 0;
    }
    int wsel = blockIdx.x >> 3;
    const float* W = (wsel == 0) ? W0 : (wsel == 1) ? W1 : W2;
    int idx = (blockIdx.x & 7) * 256 + threadIdx.x;  // 0..2047
    int slab = wsel * NF * NF;
    int l = idx & 63;
    int t = (idx >> 6) & 7;
    int s = idx >> 9;
    int kbase = s * 32 + (l >> 4) * 8;
    int nn = t * 16 + (l & 15);
    #pragma unroll
    for (int j = 0; j < 8; ++j) {
        float w = W[(kbase + j) * NF + nn];
        unsigned int h = bf16_rne(w);
        float hf = __uint_as_float(h << 16);
        unsigned int lo = bf16_rne(w - hf);
        whi[slab + idx * 8 + j] = (unsigned short)h;
        wlo[slab + idx * 8 + j] = (unsigned short)lo;
    }
}

// ---- CSR A: bucket-grouped scatter into fixed slabs via LDS reorder ----
__global__ __launch_bounds__(L1_THREADS) void k_bucket_scatter(
        const int* __restrict__ row, const int* __restrict__ colv,
        int* __restrict__ bucket_cursor, unsigned int* __restrict__ buck_arr,
        int ne, int etot, int nbuck) {
    __shared__ unsigned int hist[MAXBUCK];
    __shared__ unsigned int lbase[MAXBUCK];
    __shared__ unsigned int lcur[MAXBUCK];
    __shared__ unsigned int runb[MAXBUCK];
    __shared__ unsigned int sa[MAXBUCK], sb[MAXBUCK];
    __shared__ unsigned int reorder[L1_CHUNK];
    int t = threadIdx.x;
    int e0 = blockIdx.x * L1_CHUNK;
    int cnt_here = min(etot - e0, L1_CHUNK);

    hist[t] = 0;
    __syncthreads();

    unsigned int myv[L1_PER_THREAD];
    #pragma unroll
    for (int j = 0; j < L1_PER_THREAD; ++j) {
        int e = e0 + j * L1_THREADS + t;
        if (e < etot) {
            int s, d;
            if (e < ne) { s = row[e]; d = colv[e]; } else { s = d = e - ne; }
            myv[j] = (unsigned int)s | ((unsigned int)d << 16);
            atomicAdd(&hist[d >> 7], 1u);
        } else myv[j] = 0xffffffffu;
    }
    __syncthreads();

    sa[t] = hist[t];
    __syncthreads();
    unsigned int* pin = sa;
    unsigned int* pout = sb;
    #pragma unroll
    for (int off = 1; off < MAXBUCK; off <<= 1) {
        pout[t] = pin[t] + ((t >= off) ? pin[t - off] : 0);
        __syncthreads();
        unsigned int* tmp = pin; pin = pout; pout = tmp;
    }
    unsigned int ex = pin[t] - hist[t];
    lbase[t] = ex;
    lcur[t]  = ex;
    if (t < nbuck && hist[t] > 0)
        runb[t] = (unsigned int)atomicAdd(&bucket_cursor[t], (int)hist[t]);
    __syncthreads();

    #pragma unroll
    for (int j = 0; j < L1_PER_THREAD; ++j) {
        unsigned int v = myv[j];
        if (v != 0xffffffffu) {
            unsigned int p = atomicAdd(&lcur[v >> 23], 1u);
            reorder[p] = v;
        }
    }
    __syncthreads();

    for (int i = t; i < cnt_here; i += L1_THREADS) {
        unsigned int v = reorder[i];
        unsigned int b = v >> 23;
        buck_arr[(size_t)b * CAP + runb[b] + ((unsigned int)i - lbase[b])] = v;
    }
}

// ---- degrees + dinv only (replaces the old fine-sort kernel) ----
__global__ __launch_bounds__(256) void k_degree(const unsigned int* __restrict__ buck_arr,
                                                const int* __restrict__ bucket_cursor,
                                                float* __restrict__ dinv, int n) {
    __shared__ unsigned int cnt[128];
    int b = blockIdx.x;
    int base = b * CAP;
    int m = min(bucket_cursor[b], CAP);
    int node0 = b << 7;
    int nn = min(128, n - node0);
    int t = threadIdx.x;
    if (t < 128) cnt[t] = 0;
    __syncthreads();
    for (int i = t; i < m; i += 256)
        atomicAdd(&cnt[(buck_arr[base + i] >> 16) & 127], 1u);
    __syncthreads();
    if (t < nn) dinv[node0 + t] = rsqrtf((float)cnt[t]);  // deg >= 1 (self-loop)
}

// ---- GEMM: Out[M,128](fp8 e4m3, pre-scaled by dinv[row]) = A @ (Whi+Wlo)
// 128 rows/block, 32 rows/wave per W-fragment load (2:1 MFMA:load).
// R12: gbuf8 byte layout feat-permuted: feat F stored at byte (F&15)*8 + (F>>4),
// i.e. byte 8f+k holds feat f+16k — consumed by k_agg_bucket's atomic offsets. ----
__global__ __launch_bounds__(256) void k_gemm_mfma(const float* __restrict__ Af,
                                                   const unsigned short* __restrict__ Ab,
                                                   const unsigned short* __restrict__ Whi,
                                                   const unsigned short* __restrict__ Wlo,
                                                   const float* __restrict__ dinv,
                                                   unsigned char* __restrict__ Out,
                                                   int M) {
    __shared__ unsigned short As[128 * 136];   // 34 KB
    int tid = threadIdx.x;
    int row0 = blockIdx.x * 128;

    if (Af) {
        for (int c = tid; c < 2048; c += 256) {
            int r = c >> 4, off = c & 15;
            int gr = min(row0 + r, M - 1);
            const float4* p = (const float4*)(Af + (size_t)gr * NF) + off * 2;
            float4 v0 = p[0], v1 = p[1];
            uint4 pk;
            pk.x = pack_bf16_rne(v0.x, v0.y);
            pk.y = pack_bf16_rne(v0.z, v0.w);
            pk.z = pack_bf16_rne(v1.x, v1.y);
            pk.w = pack_bf16_rne(v1.z, v1.w);
            *(uint4*)(&As[r * 136 + off * 8]) = pk;
        }
    } else {
        for (int c = tid; c < 2048; c += 256) {
            int r = c >> 4, off = c & 15;
            int gr = min(row0 + r, M - 1);
            *(uint4*)(&As[r * 136 + off * 8]) = ((const uint4*)(Ab + (size_t)gr * NF))[off];
        }
    }
    __syncthreads();

    int wave = tid >> 6, l = tid & 63;
    int q = l >> 4, c16 = l & 15;
    int wrow0 = wave * 16;

    floatx4 acc[2][8];
    #pragma unroll
    for (int h = 0; h < 2; ++h)
        #pragma unroll
        for (int t = 0; t < 8; ++t) acc[h][t] = (floatx4){0.f, 0.f, 0.f, 0.f};

    #pragma unroll
    for (int s = 0; s < 4; ++s) {
        short8 a0 = *(const short8*)(&As[(wrow0 + c16) * 136 + s * 32 + q * 8]);
        short8 a1 = *(const short8*)(&As[(64 + wrow0 + c16) * 136 + s * 32 + q * 8]);
        #pragma unroll
        for (int t = 0; t < 8; ++t) {
            short8 bh = *(const short8*)(Whi + ((size_t)((s * 8 + t) * 64 + l) * 8));
            short8 bl = *(const short8*)(Wlo + ((size_t)((s * 8 + t) * 64 + l) * 8));
            acc[0][t] = __builtin_amdgcn_mfma_f32_16x16x32_bf16(a0, bh, acc[0][t], 0, 0, 0);
            acc[0][t] = __builtin_amdgcn_mfma_f32_16x16x32_bf16(a0, bl, acc[0][t], 0, 0, 0);
            acc[1][t] = __builtin_amdgcn_mfma_f32_16x16x32_bf16(a1, bh, acc[1][t], 0, 0, 0);
            acc[1][t] = __builtin_amdgcn_mfma_f32_16x16x32_bf16(a1, bl, acc[1][t], 0, 0, 0);
        }
    }

    #pragma unroll
    for (int h = 0; h < 2; ++h) {
        float ds[4];
        #pragma unroll
        for (int i = 0; i < 4; ++i) {
            int gr = row0 + h * 64 + wrow0 + q * 4 + i;
            ds[i] = (gr < M) ? dinv[gr] : 0.f;
        }
        #pragma unroll
        for (int t = 0; t < 8; ++t) {
            #pragma unroll
            for (int i = 0; i < 4; ++i) {
                int gr = row0 + h * 64 + wrow0 + q * 4 + i;
                if (gr < M) {
                    float v = acc[h][t][i] * ds[i];
                    unsigned int pk = __builtin_amdgcn_cvt_pk_fp8_f32(v, v, 0, false);
                    // feat F = t*16+c16 -> byte c16*8 + t (feat-permuted layout)
                    Out[(size_t)gr * NF + c16 * 8 + t] = (unsigned char)(pk & 0xffu);
                }
            }
        }
    }
}

// ---- bucket-major aggregation: block = one 128-node bucket.
// Stream unsorted slab; each edge processed exactly once. 64KB LDS f32 acc,
// ds_add_f32 accumulate (feat-permuted gbuf8 -> 16-bank spread), fused epilogue
// (dinv*acc + bias, relu, bf16) with coalesced uint4 writes. ----
__global__ __launch_bounds__(AGT) void k_agg_bucket(const unsigned char* __restrict__ hs8,
                                                    const unsigned int* __restrict__ buck_arr,
                                                    const int* __restrict__ bucket_cursor,
                                                    const float* __restrict__ dinv,
                                                    const float* __restrict__ bias,
                                                    unsigned short* __restrict__ out,
                                                    int n, int do_relu) {
    __shared__ float acc[128 * NF];   // 64 KB, indexed [node_local * 128 + feat]
    int b = blockIdx.x;
    int base = b * CAP;
    int m = min(bucket_cursor[b], CAP);
    int node0 = b << 7;
    int nn = min(128, n - node0);
    int t = threadIdx.x;

    float4 z4 = {0.f, 0.f, 0.f, 0.f};
    for (int i = t; i < 128 * NF / 4; i += AGT) ((float4*)acc)[i] = z4;
    __syncthreads();

    int grp = t >> 4;      // 0..31: edge slot group
    int f   = t & 15;      // byte-group within row (8 fp8 bytes = feats f+16k)
    const uint2* h2 = (const uint2*)hs8;

    for (int ib = 0; ib < m; ib += 128) {
        unsigned int v[4]; float mk[4];
        #pragma unroll
        for (int u = 0; u < 4; ++u) {
            int e = ib + grp + 32 * u;
            bool val = e < m;
            v[u] = buck_arr[base + (val ? e : 0)];   // m >= 1 (self-loops)
            mk[u] = val ? 1.f : 0.f;
        }
        uint2 rr[4];
        #pragma unroll
        for (int u = 0; u < 4; ++u)
            rr[u] = h2[(size_t)(v[u] & 0xffffu) * 16 + f];
        #pragma unroll
        for (int u = 0; u < 4; ++u) {
            int dl = (int)((v[u] >> 16) & 127);      // dst local to this bucket
            float* ap = acc + dl * NF;
            float mm = mk[u];
            floatx2 p0 = __builtin_amdgcn_cvt_pk_f32_fp8(rr[u].x, false);
            floatx2 p1 = __builtin_amdgcn_cvt_pk_f32_fp8(rr[u].x, true);
            floatx2 p2 = __builtin_amdgcn_cvt_pk_f32_fp8(rr[u].y, false);
            floatx2 p3 = __builtin_amdgcn_cvt_pk_f32_fp8(rr[u].y, true);
            atomicAdd(ap + f,        mm * p0.x);   // byte 8f+k = feat f+16k
            atomicAdd(ap + f + 16,   mm * p0.y);
            atomicAdd(ap + f + 32,   mm * p1.x);
            atomicAdd(ap + f + 48,   mm * p1.y);
            atomicAdd(ap + f + 64,   mm * p2.x);
            atomicAdd(ap + f + 80,   mm * p2.y);
            atomicAdd(ap + f + 96,   mm * p3.x);
            atomicAdd(ap + f + 112,  mm * p3.y);
        }
    }
    __syncthreads();

    for (int idx = t; idx < nn * 16; idx += AGT) {
        int r = idx >> 4, fq = idx & 15;
        float dd = dinv[node0 + r];
        const float* ar = acc + r * NF + fq * 8;
        float4 b0 = ((const float4*)bias)[2 * fq];
        float4 b1 = ((const float4*)bias)[2 * fq + 1];
        float o[8];
        o[0] = fmaf(dd, ar[0], b0.x); o[1] = fmaf(dd, ar[1], b0.y);
        o[2] = fmaf(dd, ar[2], b0.z); o[3] = fmaf(dd, ar[3], b0.w);
        o[4] = fmaf(dd, ar[4], b1.x); o[5] = fmaf(dd, ar[5], b1.y);
        o[6] = fmaf(dd, ar[6], b1.z); o[7] = fmaf(dd, ar[7], b1.w);
        if (do_relu) {
            #pragma unroll
            for (int j = 0; j < 8; ++j) o[j] = fmaxf(o[j], 0.f);
        }
        uint4 pk;
        pk.x = pack_bf16_rne(o[0], o[1]);
        pk.y = pack_bf16_rne(o[2], o[3]);
        pk.z = pack_bf16_rne(o[4], o[5]);
        pk.w = pack_bf16_rne(o[6], o[7]);
        ((uint4*)out)[(size_t)(node0 + r) * 16 + fq] = pk;
    }
}

// ---- pooling: deterministic partial slabs (no atomics, no memset).
// uint4 loads (16B/lane), 8-row register tile + LDS fold. ----
__global__ __launch_bounds__(128) void k_pool_partial(const unsigned short* __restrict__ h,
                                                      const int* __restrict__ batch,
                                                      float* __restrict__ pooled_part,
                                                      int n) {
    __shared__ float red[8][NF];
    int b = blockIdx.x;
    int g = b / PPG;
    int j = b % PPG;
    int t = threadIdx.x;

    int lo = 0, hi = n;
    while (lo < hi) { int mid = (lo + hi) >> 1; if (batch[mid] < g) lo = mid + 1; else hi = mid; }
    int s = lo;
    lo = s; hi = n;
    while (lo < hi) { int mid = (lo + hi) >> 1; if (batch[mid] < g + 1) lo = mid + 1; else hi = mid; }
    int e = lo;

    int len = e - s;
    int chunk = (len + PPG - 1) / PPG;
    int i0 = s + j * chunk;
    int i1 = min(e, i0 + chunk);

    int r = t >> 4, f8 = t & 15;
    float acc[8];
    #pragma unroll
    for (int k = 0; k < 8; ++k) acc[k] = 0.f;
    for (int i = i0 + r; i < i1; i += 8) {
        uint4 v = *(const uint4*)(&h[(size_t)i * NF + f8 * 8]);
        acc[0] += bf16u_to_f32(v.x & 0xffffu); acc[1] += bf16u_to_f32(v.x >> 16);
        acc[2] += bf16u_to_f32(v.y & 0xffffu); acc[3] += bf16u_to_f32(v.y >> 16);
        acc[4] += bf16u_to_f32(v.z & 0xffffu); acc[5] += bf16u_to_f32(v.z >> 16);
        acc[6] += bf16u_to_f32(v.w & 0xffffu); acc[7] += bf16u_to_f32(v.w >> 16);
    }
    #pragma unroll
    for (int k = 0; k < 8; ++k) red[r][f8 * 8 + k] = acc[k];
    __syncthreads();
    float ssum = 0.f;
    #pragma unroll
    for (int rr = 0; rr < 8; ++rr) ssum += red[rr][t];
    pooled_part[(size_t)b * NF + t] = ssum;
}

// ---- head: fold partials in LDS, counts + linear 128x16 + softmax ----
__global__ __launch_bounds__(1024) void k_head(const float* __restrict__ pooled_part,
                                               const int* __restrict__ batch,
                                               const float* __restrict__ linW,
                                               const float* __restrict__ linb,
                                               float* __restrict__ out,
                                               int n, int n_graphs) {
    __shared__ float ph[64 * NF];  // 32 KB
    int t = threadIdx.x;
    for (int i = t; i < n_graphs * NF; i += 1024) {
        int g = i >> 7, f = i & 127;
        float s = 0.f;
        #pragma unroll
        for (int j = 0; j < PPG; ++j)
            s += pooled_part[(size_t)(g * PPG + j) * NF + f];
        ph[i] = s;
    }
    __syncthreads();

    int g = t >> 4;
    int c = t & 15;

    int lo = 0, hi = n;
    while (lo < hi) { int mid = (lo + hi) >> 1; if (batch[mid] < g) lo = mid + 1; else hi = mid; }
    int start = lo;
    lo = start; hi = n;
    while (lo < hi) { int mid = (lo + hi) >> 1; if (batch[mid] < g + 1) lo = mid + 1; else hi = mid; }
    float inv_cnt = 1.f / fmaxf((float)(lo - start), 1.f);

    float acc = linb[c];
    for (int k = 0; k < NF; ++k)
        acc += ph[g * NF + k] * inv_cnt * linW[k * 16 + c];

    float m = acc;
    #pragma unroll
    for (int s2 = 8; s2 >= 1; s2 >>= 1) m = fmaxf(m, __shfl_xor(m, s2, 16));
    float e = expf(acc - m);
    float ssum = e;
    #pragma unroll
    for (int s2 = 8; s2 >= 1; s2 >>= 1) ssum += __shfl_xor(ssum, s2, 16);
    out[g * 16 + c] = e / ssum;
}

extern "C" void kernel_launch(void* const* d_in, const int* in_sizes, int n_in,
                              void* d_out, int out_size, void* d_ws, size_t ws_size,
                              hipStream_t stream) {
    const float* x    = (const float*)d_in[0];
    const int*   edge = (const int*)d_in[1];
    const int*   batch= (const int*)d_in[2];
    const float* W0   = (const float*)d_in[3];
    const float* b0   = (const float*)d_in[4];
    const float* W1   = (const float*)d_in[5];
    const float* b1   = (const float*)d_in[6];
    const float* W2   = (const float*)d_in[7];
    const float* b2   = (const float*)d_in[8];
    const float* linW = (const float*)d_in[9];
    const float* linb = (const float*)d_in[10];

    int n  = in_sizes[0] / NF;       // 50000
    int ne = in_sizes[1] / 2;        // 800000
    int n_graphs = out_size / 16;    // 64
    const int* row  = edge;
    const int* colv = edge + ne;
    int etot = ne + n;
    int nbuck = (n + 127) >> 7;      // 391

    char* p = (char*)d_ws;
    auto alloc = [&](size_t bytes) { char* r = p; p += (bytes + 255) & ~(size_t)255; return r; };
    int*   bucket_cursor = (int*)alloc((size_t)(MAXBUCK + 1) * 4);
    unsigned int* buck_arr = (unsigned int*)alloc((size_t)MAXBUCK * CAP * 4);
    float* dinv    = (float*)alloc((size_t)n * 4);
    unsigned char*  gbuf8 = (unsigned char*) alloc((size_t)n * NF);      // fp8 gemm out (feat-permuted)
    unsigned short* abuf  = (unsigned short*)alloc((size_t)n * NF * 2);  // bf16 agg out
    float* pooled_part = (float*)alloc((size_t)n_graphs * PPG * NF * 4);
    unsigned short* whi = (unsigned short*)alloc((size_t)3 * NF * NF * 2);
    unsigned short* wlo = (unsigned short*)alloc((size_t)3 * NF * NF * 2);

    // repack first (block 0 also zeroes bucket cursors)
    k_repack_w3<<<24, 256, 0, stream>>>(W0, W1, W2, whi, wlo, bucket_cursor);

    // CSR build (slab buckets) + degrees
    k_bucket_scatter<<<(etot + L1_CHUNK - 1) / L1_CHUNK, L1_THREADS, 0, stream>>>(
        row, colv, bucket_cursor, buck_arr, ne, etot, nbuck);
    k_degree<<<nbuck, 256, 0, stream>>>(buck_arr, bucket_cursor, dinv, n);

    int gemm_blocks = (n + 127) / 128;
    const size_t WSLAB = (size_t)NF * NF;

    k_gemm_mfma<<<gemm_blocks, 256, 0, stream>>>(x, nullptr, whi, wlo, dinv, gbuf8, n);
    k_agg_bucket<<<nbuck, AGT, 0, stream>>>(gbuf8, buck_arr, bucket_cursor, dinv, b0, abuf, n, 1);
    k_gemm_mfma<<<gemm_blocks, 256, 0, stream>>>(nullptr, abuf, whi + WSLAB, wlo + WSLAB, dinv, gbuf8, n);
    k_agg_bucket<<<nbuck, AGT, 0, stream>>>(gbuf8, buck_arr, bucket_cursor, dinv, b1, abuf, n, 1);
    k_gemm_mfma<<<gemm_blocks, 256, 0, stream>>>(nullptr, abuf, whi + 2 * WSLAB, wlo + 2 * WSLAB, dinv, gbuf8, n);
    k_agg_bucket<<<nbuck, AGT, 0, stream>>>(gbuf8, buck_arr, bucket_cursor, dinv, b2, abuf, n, 0);

    // pool (no atomics/memset) + head
    k_pool_partial<<<n_graphs * PPG, 128, 0, stream>>>(abuf, batch, pooled_part, n);
    k_head<<<1, 1024, 0, stream>>>(pooled_part, batch, linW, linb, (float*)d_out, n, n_graphs);
}

// Round 4
// 517.043 us; speedup vs baseline: 4.7491x; 4.7491x over previous
//
#include <hip/hip_runtime.h>

// GCN: 3x (GEMM 128x128 + normalized scatter-sum) + mean-pool + linear + softmax.
// R1: two-stage pool. R2: parallel scan. R3: bf16 + split-W MFMA GEMM.
// R4: agg multi-edge-in-flight; h pre-scaled by dinv. R5: CSR via two-level bucket sort.
// R6 FAILED (fusion cut gather parallelism). R7/R8: 16/32 edges in flight (neutral ->
// agg latency-hidden at a cheap floor). R9: fp8 e4m3 gather payload (292us).
// R10 FAILED (cooperative 10x grid.sync flushed per-XCD L2s: 505MB HBM/dispatch).
// R11: gemm 128-row blocks (2:1 MFMA:W-load), pool uint4, scatter 4096-chunks (277us).
// R12 FAILED (bucket-major LDS-atomic agg: 128 LDS f32 RMW/edge, dst-collision
//     serialization -> 751us/agg; old per-node-wave gather agg is the right shape).
// R13: R11 verbatim + layer-3 agg accumulates directly into pooled_part slabs via
//      global f32 atomics (kills k_pool_partial + abuf roundtrip for layer 3;
//      ~98 serialized RMW/address over 65K addresses, 1-2us). pooled_part zeroed
//      in k_repack_w3. Pool sum is now fp32-accurate (no bf16 roundtrip).
// Assumes n <= 65536 (src packed u16), n <= 512*128, bucket load < CAP (8.5σ).

#define NF 128
#define MAXBUCK 512
#define CAP 2560           // slab capacity per bucket (mean 2176, sigma ~45)
#define L1_CHUNK 4096
#define L1_THREADS 512
#define L1_PER_THREAD 8    // L1_CHUNK / L1_THREADS
#define PPG 8              // pool partials per graph

typedef __attribute__((ext_vector_type(8))) short short8;
typedef __attribute__((ext_vector_type(4))) float floatx4;
typedef __attribute__((ext_vector_type(2))) float floatx2;

__device__ __forceinline__ unsigned int bf16_rne(float x) {
    unsigned int u = __float_as_uint(x);
    return (u + 0x7fffu + ((u >> 16) & 1u)) >> 16;
}
__device__ __forceinline__ unsigned int pack_bf16_rne(float x, float y) {
    return bf16_rne(x) | (bf16_rne(y) << 16);
}
__device__ __forceinline__ float bf16u_to_f32(unsigned int u) {
    return __uint_as_float(u << 16);
}

// ---- repack all 3 W (fp32 [k][n]) into B-fragment-major bf16 hi/lo.
// Also zeroes bucket cursors (block 0) and pooled_part (all blocks). ----
__global__ __launch_bounds__(256) void k_repack_w3(const float* __restrict__ W0,
                                                   const float* __restrict__ W1,
                                                   const float* __restrict__ W2,
                                                   unsigned short* __restrict__ whi,
                                                   unsigned short* __restrict__ wlo,
                                                   int* __restrict__ bucket_cursor,
                                                   float* __restrict__ pooled_part,
                                                   int npool4) {
    if (blockIdx.x == 0) {
        for (int i = threadIdx.x; i <= MAXBUCK; i += 256) bucket_cursor[i] = 0;
    }
    float4 z4 = {0.f, 0.f, 0.f, 0.f};
    for (int i = blockIdx.x * 256 + threadIdx.x; i < npool4; i += 24 * 256)
        ((float4*)pooled_part)[i] = z4;

    int wsel = blockIdx.x >> 3;
    const float* W = (wsel == 0) ? W0 : (wsel == 1) ? W1 : W2;
    int idx = (blockIdx.x & 7) * 256 + threadIdx.x;  // 0..2047
    int slab = wsel * NF * NF;
    int l = idx & 63;
    int t = (idx >> 6) & 7;
    int s = idx >> 9;
    int kbase = s * 32 + (l >> 4) * 8;
    int nn = t * 16 + (l & 15);
    #pragma unroll
    for (int j = 0; j < 8; ++j) {
        float w = W[(kbase + j) * NF + nn];
        unsigned int h = bf16_rne(w);
        float hf = __uint_as_float(h << 16);
        unsigned int lo = bf16_rne(w - hf);
        whi[slab + idx * 8 + j] = (unsigned short)h;
        wlo[slab + idx * 8 + j] = (unsigned short)lo;
    }
}

// ---- CSR A: bucket-grouped scatter into fixed slabs via LDS reorder ----
__global__ __launch_bounds__(L1_THREADS) void k_bucket_scatter(
        const int* __restrict__ row, const int* __restrict__ colv,
        int* __restrict__ bucket_cursor, unsigned int* __restrict__ buck_arr,
        int ne, int etot, int nbuck) {
    __shared__ unsigned int hist[MAXBUCK];
    __shared__ unsigned int lbase[MAXBUCK];
    __shared__ unsigned int lcur[MAXBUCK];
    __shared__ unsigned int runb[MAXBUCK];
    __shared__ unsigned int sa[MAXBUCK], sb[MAXBUCK];
    __shared__ unsigned int reorder[L1_CHUNK];
    int t = threadIdx.x;
    int e0 = blockIdx.x * L1_CHUNK;
    int cnt_here = min(etot - e0, L1_CHUNK);

    hist[t] = 0;
    __syncthreads();

    unsigned int myv[L1_PER_THREAD];
    #pragma unroll
    for (int j = 0; j < L1_PER_THREAD; ++j) {
        int e = e0 + j * L1_THREADS + t;
        if (e < etot) {
            int s, d;
            if (e < ne) { s = row[e]; d = colv[e]; } else { s = d = e - ne; }
            myv[j] = (unsigned int)s | ((unsigned int)d << 16);
            atomicAdd(&hist[d >> 7], 1u);
        } else myv[j] = 0xffffffffu;
    }
    __syncthreads();

    sa[t] = hist[t];
    __syncthreads();
    unsigned int* pin = sa;
    unsigned int* pout = sb;
    #pragma unroll
    for (int off = 1; off < MAXBUCK; off <<= 1) {
        pout[t] = pin[t] + ((t >= off) ? pin[t - off] : 0);
        __syncthreads();
        unsigned int* tmp = pin; pin = pout; pout = tmp;
    }
    unsigned int ex = pin[t] - hist[t];
    lbase[t] = ex;
    lcur[t]  = ex;
    if (t < nbuck && hist[t] > 0)
        runb[t] = (unsigned int)atomicAdd(&bucket_cursor[t], (int)hist[t]);
    __syncthreads();

    #pragma unroll
    for (int j = 0; j < L1_PER_THREAD; ++j) {
        unsigned int v = myv[j];
        if (v != 0xffffffffu) {
            unsigned int p = atomicAdd(&lcur[v >> 23], 1u);
            reorder[p] = v;
        }
    }
    __syncthreads();

    for (int i = t; i < cnt_here; i += L1_THREADS) {
        unsigned int v = reorder[i];
        unsigned int b = v >> 23;
        buck_arr[(size_t)b * CAP + runb[b] + ((unsigned int)i - lbase[b])] = v;
    }
}

// ---- CSR B: per-bucket fine sort; emits src16 (slab-local), starts/ends/dinv ----
__global__ __launch_bounds__(256) void k_fine(const unsigned int* __restrict__ buck_arr,
                                              const int* __restrict__ bucket_cursor,
                                              int* __restrict__ starts,
                                              int* __restrict__ ends,
                                              float* __restrict__ dinv,
                                              unsigned short* __restrict__ src16,
                                              int n) {
    int b = blockIdx.x;
    int base = b * CAP;
    int m = min(bucket_cursor[b], CAP);
    int node0 = b << 7;
    int nn = min(128, n - node0);
    __shared__ unsigned int cnt[128];
    __shared__ unsigned int lsc[256];
    __shared__ unsigned int lcur[128];
    __shared__ unsigned short srcbuf[CAP];
    int t = threadIdx.x;
    if (t < 128) cnt[t] = 0;
    __syncthreads();
    for (int i = t; i < m; i += 256)
        atomicAdd(&cnt[(buck_arr[base + i] >> 16) - node0], 1u);
    __syncthreads();
    unsigned int v0 = (t < 128) ? cnt[t] : 0;
    lsc[t] = v0;
    __syncthreads();
    #pragma unroll
    for (int off = 1; off < 128; off <<= 1) {
        unsigned int add = (t >= off) ? lsc[t - off] : 0;
        __syncthreads();
        lsc[t] += add;
        __syncthreads();
    }
    if (t < 128) {
        unsigned int ex = lsc[t] - v0;
        lcur[t] = ex;
        if (t < nn) {
            starts[node0 + t] = base + (int)ex;
            ends[node0 + t]   = base + (int)(ex + v0);
            dinv[node0 + t]   = rsqrtf((float)v0);   // deg >= 1 (self-loop)
        }
    }
    __syncthreads();
    for (int i = t; i < m; i += 256) {
        unsigned int v = buck_arr[base + i];
        unsigned int p = atomicAdd(&lcur[(v >> 16) - node0], 1u);
        srcbuf[p] = (unsigned short)(v & 0xffffu);
    }
    __syncthreads();
    for (int i = t; i < m; i += 256)
        src16[base + i] = srcbuf[i];
}

// ---- GEMM: Out[M,128](fp8 e4m3, pre-scaled by dinv[row]) = A @ (Whi+Wlo)
// 128 rows/block, 32 rows/wave per W-fragment load (2:1 MFMA:load). ----
__global__ __launch_bounds__(256) void k_gemm_mfma(const float* __restrict__ Af,
                                                   const unsigned short* __restrict__ Ab,
                                                   const unsigned short* __restrict__ Whi,
                                                   const unsigned short* __restrict__ Wlo,
                                                   const float* __restrict__ dinv,
                                                   unsigned char* __restrict__ Out,
                                                   int M) {
    __shared__ unsigned short As[128 * 136];   // 34 KB
    int tid = threadIdx.x;
    int row0 = blockIdx.x * 128;

    if (Af) {
        for (int c = tid; c < 2048; c += 256) {
            int r = c >> 4, off = c & 15;
            int gr = min(row0 + r, M - 1);
            const float4* p = (const float4*)(Af + (size_t)gr * NF) + off * 2;
            float4 v0 = p[0], v1 = p[1];
            uint4 pk;
            pk.x = pack_bf16_rne(v0.x, v0.y);
            pk.y = pack_bf16_rne(v0.z, v0.w);
            pk.z = pack_bf16_rne(v1.x, v1.y);
            pk.w = pack_bf16_rne(v1.z, v1.w);
            *(uint4*)(&As[r * 136 + off * 8]) = pk;
        }
    } else {
        for (int c = tid; c < 2048; c += 256) {
            int r = c >> 4, off = c & 15;
            int gr = min(row0 + r, M - 1);
            *(uint4*)(&As[r * 136 + off * 8]) = ((const uint4*)(Ab + (size_t)gr * NF))[off];
        }
    }
    __syncthreads();

    int wave = tid >> 6, l = tid & 63;
    int q = l >> 4, c16 = l & 15;
    int wrow0 = wave * 16;

    floatx4 acc[2][8];
    #pragma unroll
    for (int h = 0; h < 2; ++h)
        #pragma unroll
        for (int t = 0; t < 8; ++t) acc[h][t] = (floatx4){0.f, 0.f, 0.f, 0.f};

    #pragma unroll
    for (int s = 0; s < 4; ++s) {
        short8 a0 = *(const short8*)(&As[(wrow0 + c16) * 136 + s * 32 + q * 8]);
        short8 a1 = *(const short8*)(&As[(64 + wrow0 + c16) * 136 + s * 32 + q * 8]);
        #pragma unroll
        for (int t = 0; t < 8; ++t) {
            short8 bh = *(const short8*)(Whi + ((size_t)((s * 8 + t) * 64 + l) * 8));
            short8 bl = *(const short8*)(Wlo + ((size_t)((s * 8 + t) * 64 + l) * 8));
            acc[0][t] = __builtin_amdgcn_mfma_f32_16x16x32_bf16(a0, bh, acc[0][t], 0, 0, 0);
            acc[0][t] = __builtin_amdgcn_mfma_f32_16x16x32_bf16(a0, bl, acc[0][t], 0, 0, 0);
            acc[1][t] = __builtin_amdgcn_mfma_f32_16x16x32_bf16(a1, bh, acc[1][t], 0, 0, 0);
            acc[1][t] = __builtin_amdgcn_mfma_f32_16x16x32_bf16(a1, bl, acc[1][t], 0, 0, 0);
        }
    }

    #pragma unroll
    for (int h = 0; h < 2; ++h) {
        float ds[4];
        #pragma unroll
        for (int i = 0; i < 4; ++i) {
            int gr = row0 + h * 64 + wrow0 + q * 4 + i;
            ds[i] = (gr < M) ? dinv[gr] : 0.f;
        }
        #pragma unroll
        for (int t = 0; t < 8; ++t) {
            #pragma unroll
            for (int i = 0; i < 4; ++i) {
                int gr = row0 + h * 64 + wrow0 + q * 4 + i;
                if (gr < M) {
                    float v = acc[h][t][i] * ds[i];
                    unsigned int pk = __builtin_amdgcn_cvt_pk_fp8_f32(v, v, 0, false);
                    Out[(size_t)gr * NF + t * 16 + c16] = (unsigned char)(pk & 0xffu);
                }
            }
        }
    }
}

// ---- out[i] = relu?( dinv[i] * sum_e h8[src_e] + b ), h8 fp8 pre-scaled.
// One wave/node; lane = (slot g=l>>4, feat f=l&15); uint2 (8 fp8 feats)/lane;
// 4 slots x unroll 8 = 32 edges in flight. Tail via 0/1 fma mask.
// R13: if pooled != nullptr (layer 3), atomically accumulate result into
// pooled_part[(graph*PPG + (node&7)) * NF + feat] instead of writing abuf. ----
__global__ __launch_bounds__(256) void k_agg_fp8(const unsigned char* __restrict__ hs8,
                                                 const int* __restrict__ starts,
                                                 const int* __restrict__ ends,
                                                 const unsigned short* __restrict__ src16,
                                                 const float* __restrict__ dinv,
                                                 const float* __restrict__ bias,
                                                 unsigned short* __restrict__ out,
                                                 const int* __restrict__ batch,
                                                 float* __restrict__ pooled,
                                                 int n, int do_relu) {
    int wave = threadIdx.x >> 6;
    int lane = threadIdx.x & 63;
    int node = blockIdx.x * 4 + wave;
    if (node >= n) return;
    int g = lane >> 4;
    int f = lane & 15;
    int start = starts[node], end = ends[node];

    const uint2* h2 = (const uint2*)hs8;   // 16 uint2 per 128-feat fp8 row
    float acc[8];
    #pragma unroll
    for (int j = 0; j < 8; ++j) acc[j] = 0.f;

    for (int base = start; base < end; base += 32) {
        int   sidx[8];
        float msk[8];
        #pragma unroll
        for (int j = 0; j < 8; ++j) {
            int e = base + g + 4 * j;
            bool v = e < end;
            sidx[j] = (int)src16[v ? e : start];  // masked slots reload a VALID row (no NaN decode)
            msk[j]  = v ? 1.f : 0.f;
        }
        uint2 rr[8];
        #pragma unroll
        for (int j = 0; j < 8; ++j)
            rr[j] = h2[(size_t)sidx[j] * 16 + f];
        #pragma unroll
        for (int j = 0; j < 8; ++j) {
            float m = msk[j];
            floatx2 p0 = __builtin_amdgcn_cvt_pk_f32_fp8(rr[j].x, false);
            floatx2 p1 = __builtin_amdgcn_cvt_pk_f32_fp8(rr[j].x, true);
            floatx2 p2 = __builtin_amdgcn_cvt_pk_f32_fp8(rr[j].y, false);
            floatx2 p3 = __builtin_amdgcn_cvt_pk_f32_fp8(rr[j].y, true);
            acc[0] = fmaf(m, p0.x, acc[0]);
            acc[1] = fmaf(m, p0.y, acc[1]);
            acc[2] = fmaf(m, p1.x, acc[2]);
            acc[3] = fmaf(m, p1.y, acc[3]);
            acc[4] = fmaf(m, p2.x, acc[4]);
            acc[5] = fmaf(m, p2.y, acc[5]);
            acc[6] = fmaf(m, p3.x, acc[6]);
            acc[7] = fmaf(m, p3.y, acc[7]);
        }
    }

    // fold the 4 edge slots (lanes 16 apart hold the same feat group)
    #pragma unroll
    for (int j = 0; j < 8; ++j) {
        acc[j] += __shfl_xor(acc[j], 16);
        acc[j] += __shfl_xor(acc[j], 32);
    }

    if (g == 0) {
        float dd = dinv[node];
        float4 b0 = ((const float4*)bias)[2 * f];
        float4 b1 = ((const float4*)bias)[2 * f + 1];
        float r[8];
        r[0] = fmaf(dd, acc[0], b0.x); r[1] = fmaf(dd, acc[1], b0.y);
        r[2] = fmaf(dd, acc[2], b0.z); r[3] = fmaf(dd, acc[3], b0.w);
        r[4] = fmaf(dd, acc[4], b1.x); r[5] = fmaf(dd, acc[5], b1.y);
        r[6] = fmaf(dd, acc[6], b1.z); r[7] = fmaf(dd, acc[7], b1.w);
        if (do_relu) {
            #pragma unroll
            for (int j = 0; j < 8; ++j) r[j] = fmaxf(r[j], 0.f);
        }
        if (pooled) {
            int slab = (batch[node] * PPG + (node & (PPG - 1))) * NF + f * 8;
            #pragma unroll
            for (int j = 0; j < 8; ++j) atomicAdd(&pooled[slab + j], r[j]);
        } else {
            uint4 pk;
            pk.x = pack_bf16_rne(r[0], r[1]);
            pk.y = pack_bf16_rne(r[2], r[3]);
            pk.z = pack_bf16_rne(r[4], r[5]);
            pk.w = pack_bf16_rne(r[6], r[7]);
            ((uint4*)out)[(size_t)node * 16 + f] = pk;
        }
    }
}

// ---- head: fold partials in LDS, counts + linear 128x16 + softmax ----
__global__ __launch_bounds__(1024) void k_head(const float* __restrict__ pooled_part,
                                               const int* __restrict__ batch,
                                               const float* __restrict__ linW,
                                               const float* __restrict__ linb,
                                               float* __restrict__ out,
                                               int n, int n_graphs) {
    __shared__ float ph[64 * NF];  // 32 KB
    int t = threadIdx.x;
    for (int i = t; i < n_graphs * NF; i += 1024) {
        int g = i >> 7, f = i & 127;
        float s = 0.f;
        #pragma unroll
        for (int j = 0; j < PPG; ++j)
            s += pooled_part[(size_t)(g * PPG + j) * NF + f];
        ph[i] = s;
    }
    __syncthreads();

    int g = t >> 4;
    int c = t & 15;

    int lo = 0, hi = n;
    while (lo < hi) { int mid = (lo + hi) >> 1; if (batch[mid] < g) lo = mid + 1; else hi = mid; }
    int start = lo;
    lo = start; hi = n;
    while (lo < hi) { int mid = (lo + hi) >> 1; if (batch[mid] < g + 1) lo = mid + 1; else hi = mid; }
    float inv_cnt = 1.f / fmaxf((float)(lo - start), 1.f);

    float acc = linb[c];
    for (int k = 0; k < NF; ++k)
        acc += ph[g * NF + k] * inv_cnt * linW[k * 16 + c];

    float m = acc;
    #pragma unroll
    for (int s2 = 8; s2 >= 1; s2 >>= 1) m = fmaxf(m, __shfl_xor(m, s2, 16));
    float e = expf(acc - m);
    float ssum = e;
    #pragma unroll
    for (int s2 = 8; s2 >= 1; s2 >>= 1) ssum += __shfl_xor(ssum, s2, 16);
    out[g * 16 + c] = e / ssum;
}

extern "C" void kernel_launch(void* const* d_in, const int* in_sizes, int n_in,
                              void* d_out, int out_size, void* d_ws, size_t ws_size,
                              hipStream_t stream) {
    const float* x    = (const float*)d_in[0];
    const int*   edge = (const int*)d_in[1];
    const int*   batch= (const int*)d_in[2];
    const float* W0   = (const float*)d_in[3];
    const float* b0   = (const float*)d_in[4];
    const float* W1   = (const float*)d_in[5];
    const float* b1   = (const float*)d_in[6];
    const float* W2   = (const float*)d_in[7];
    const float* b2   = (const float*)d_in[8];
    const float* linW = (const float*)d_in[9];
    const float* linb = (const float*)d_in[10];

    int n  = in_sizes[0] / NF;       // 50000
    int ne = in_sizes[1] / 2;        // 800000
    int n_graphs = out_size / 16;    // 64
    const int* row  = edge;
    const int* colv = edge + ne;
    int etot = ne + n;
    int nbuck = (n + 127) >> 7;      // 391

    char* p = (char*)d_ws;
    auto alloc = [&](size_t bytes) { char* r = p; p += (bytes + 255) & ~(size_t)255; return r; };
    int*   bucket_cursor = (int*)alloc((size_t)(MAXBUCK + 1) * 4);
    unsigned int* buck_arr = (unsigned int*)alloc((size_t)MAXBUCK * CAP * 4);
    unsigned short* src16  = (unsigned short*)alloc((size_t)MAXBUCK * CAP * 2);
    int*   starts  = (int*)  alloc((size_t)n * 4);
    int*   ends    = (int*)  alloc((size_t)n * 4);
    float* dinv    = (float*)alloc((size_t)n * 4);
    unsigned char*  gbuf8 = (unsigned char*) alloc((size_t)n * NF);      // fp8 gemm out
    unsigned short* abuf  = (unsigned short*)alloc((size_t)n * NF * 2);  // bf16 agg out (layers 1-2)
    float* pooled_part = (float*)alloc((size_t)n_graphs * PPG * NF * 4);
    unsigned short* whi = (unsigned short*)alloc((size_t)3 * NF * NF * 2);
    unsigned short* wlo = (unsigned short*)alloc((size_t)3 * NF * NF * 2);

    // repack first (also zeroes bucket cursors + pooled_part)
    int npool4 = n_graphs * PPG * NF / 4;
    k_repack_w3<<<24, 256, 0, stream>>>(W0, W1, W2, whi, wlo, bucket_cursor,
                                        pooled_part, npool4);

    // CSR build (slab buckets)
    k_bucket_scatter<<<(etot + L1_CHUNK - 1) / L1_CHUNK, L1_THREADS, 0, stream>>>(
        row, colv, bucket_cursor, buck_arr, ne, etot, nbuck);
    k_fine<<<nbuck, 256, 0, stream>>>(buck_arr, bucket_cursor, starts, ends, dinv, src16, n);

    int gemm_blocks = (n + 127) / 128;
    int agg_blocks  = (n + 3) / 4;
    const size_t WSLAB = (size_t)NF * NF;

    k_gemm_mfma<<<gemm_blocks, 256, 0, stream>>>(x, nullptr, whi, wlo, dinv, gbuf8, n);
    k_agg_fp8  <<<agg_blocks, 256, 0, stream>>>(gbuf8, starts, ends, src16, dinv, b0, abuf,
                                                batch, nullptr, n, 1);
    k_gemm_mfma<<<gemm_blocks, 256, 0, stream>>>(nullptr, abuf, whi + WSLAB, wlo + WSLAB, dinv, gbuf8, n);
    k_agg_fp8  <<<agg_blocks, 256, 0, stream>>>(gbuf8, starts, ends, src16, dinv, b1, abuf,
                                                batch, nullptr, n, 1);
    k_gemm_mfma<<<gemm_blocks, 256, 0, stream>>>(nullptr, abuf, whi + 2 * WSLAB, wlo + 2 * WSLAB, dinv, gbuf8, n);
    k_agg_fp8  <<<agg_blocks, 256, 0, stream>>>(gbuf8, starts, ends, src16, dinv, b2, abuf,
                                                batch, pooled_part, n, 0);

    // head (pool partials already accumulated by layer-3 agg)
    k_head<<<1, 1024, 0, stream>>>(pooled_part, batch, linW, linb, (float*)d_out, n, n_graphs);
}

// Round 5
// 315.563 us; speedup vs baseline: 7.7812x; 1.6385x over previous
//
#include <hip/hip_runtime.h>

// GCN: 3x (GEMM 128x128 + normalized scatter-sum) + mean-pool + linear + softmax.
// R1: two-stage pool. R2: parallel scan. R3: bf16 + split-W MFMA GEMM.
// R4: agg multi-edge-in-flight; h pre-scaled by dinv. R5: CSR via two-level bucket sort.
// R6 FAILED (fusion cut gather parallelism). R7/R8: 16/32 edges in flight (neutral ->
// agg latency-hidden). R9: fp8 e4m3 gather payload (292us).
// R10 FAILED (cooperative grid.sync flushed per-XCD L2s: 505MB HBM/dispatch).
// R11: gemm 128-row blocks (2:1 MFMA:W-load), pool uint4, scatter 4096-chunks (277us).
// R12 FAILED (bucket-major LDS-atomic agg: dst-collision RMW serialization, 751us).
// R13 FAILED (layer-3 pool via global f32 atomics: 6.4M device-scope atomics =
//     ~400MB cross-XCD coherence traffic -> agg3 290us. Lesson: keep accumulation
//     in wave-private registers, always).
// R14: R11 verbatim + feature-split agg: each agg runs as 2 passes (fsel=0/1),
//     each gathering a 64B half-row from a 3.2MB half of gbuf8 -> fits 4MB
//     per-XCD L2 (R13 counters showed 33MB HBM refetch/agg = L2 thrash at 6.4MB
//     working set). Bit-identical numerics; only lane<->feature mapping changes.
// Assumes n <= 65536 (src packed u16), n <= 512*128, bucket load < CAP (8.5σ).

#define NF 128
#define MAXBUCK 512
#define CAP 2560           // slab capacity per bucket (mean 2176, sigma ~45)
#define L1_CHUNK 4096
#define L1_THREADS 512
#define L1_PER_THREAD 8    // L1_CHUNK / L1_THREADS
#define PPG 8              // pool partials per graph

typedef __attribute__((ext_vector_type(8))) short short8;
typedef __attribute__((ext_vector_type(4))) float floatx4;
typedef __attribute__((ext_vector_type(2))) float floatx2;

__device__ __forceinline__ unsigned int bf16_rne(float x) {
    unsigned int u = __float_as_uint(x);
    return (u + 0x7fffu + ((u >> 16) & 1u)) >> 16;
}
__device__ __forceinline__ unsigned int pack_bf16_rne(float x, float y) {
    return bf16_rne(x) | (bf16_rne(y) << 16);
}
__device__ __forceinline__ float bf16u_to_f32(unsigned int u) {
    return __uint_as_float(u << 16);
}

// ---- repack all 3 W (fp32 [k][n]) into B-fragment-major bf16 hi/lo.
// Block 0 also zeroes the bucket cursors — runs before scatter. ----
__global__ __launch_bounds__(256) void k_repack_w3(const float* __restrict__ W0,
                                                   const float* __restrict__ W1,
                                                   const float* __restrict__ W2,
                                                   unsigned short* __restrict__ whi,
                                                   unsigned short* __restrict__ wlo,
                                                   int* __restrict__ bucket_cursor) {
    if (blockIdx.x == 0) {
        for (int i = threadIdx.x; i <= MAXBUCK; i += 256) bucket_cursor[i] = 0;
    }
    int wsel = blockIdx.x >> 3;
    const float* W = (wsel == 0) ? W0 : (wsel == 1) ? W1 : W2;
    int idx = (blockIdx.x & 7) * 256 + threadIdx.x;  // 0..2047
    int slab = wsel * NF * NF;
    int l = idx & 63;
    int t = (idx >> 6) & 7;
    int s = idx >> 9;
    int kbase = s * 32 + (l >> 4) * 8;
    int nn = t * 16 + (l & 15);
    #pragma unroll
    for (int j = 0; j < 8; ++j) {
        float w = W[(kbase + j) * NF + nn];
        unsigned int h = bf16_rne(w);
        float hf = __uint_as_float(h << 16);
        unsigned int lo = bf16_rne(w - hf);
        whi[slab + idx * 8 + j] = (unsigned short)h;
        wlo[slab + idx * 8 + j] = (unsigned short)lo;
    }
}

// ---- CSR A: bucket-grouped scatter into fixed slabs via LDS reorder ----
__global__ __launch_bounds__(L1_THREADS) void k_bucket_scatter(
        const int* __restrict__ row, const int* __restrict__ colv,
        int* __restrict__ bucket_cursor, unsigned int* __restrict__ buck_arr,
        int ne, int etot, int nbuck) {
    __shared__ unsigned int hist[MAXBUCK];
    __shared__ unsigned int lbase[MAXBUCK];
    __shared__ unsigned int lcur[MAXBUCK];
    __shared__ unsigned int runb[MAXBUCK];
    __shared__ unsigned int sa[MAXBUCK], sb[MAXBUCK];
    __shared__ unsigned int reorder[L1_CHUNK];
    int t = threadIdx.x;
    int e0 = blockIdx.x * L1_CHUNK;
    int cnt_here = min(etot - e0, L1_CHUNK);

    hist[t] = 0;
    __syncthreads();

    unsigned int myv[L1_PER_THREAD];
    #pragma unroll
    for (int j = 0; j < L1_PER_THREAD; ++j) {
        int e = e0 + j * L1_THREADS + t;
        if (e < etot) {
            int s, d;
            if (e < ne) { s = row[e]; d = colv[e]; } else { s = d = e - ne; }
            myv[j] = (unsigned int)s | ((unsigned int)d << 16);
            atomicAdd(&hist[d >> 7], 1u);
        } else myv[j] = 0xffffffffu;
    }
    __syncthreads();

    sa[t] = hist[t];
    __syncthreads();
    unsigned int* pin = sa;
    unsigned int* pout = sb;
    #pragma unroll
    for (int off = 1; off < MAXBUCK; off <<= 1) {
        pout[t] = pin[t] + ((t >= off) ? pin[t - off] : 0);
        __syncthreads();
        unsigned int* tmp = pin; pin = pout; pout = tmp;
    }
    unsigned int ex = pin[t] - hist[t];
    lbase[t] = ex;
    lcur[t]  = ex;
    if (t < nbuck && hist[t] > 0)
        runb[t] = (unsigned int)atomicAdd(&bucket_cursor[t], (int)hist[t]);
    __syncthreads();

    #pragma unroll
    for (int j = 0; j < L1_PER_THREAD; ++j) {
        unsigned int v = myv[j];
        if (v != 0xffffffffu) {
            unsigned int p = atomicAdd(&lcur[v >> 23], 1u);
            reorder[p] = v;
        }
    }
    __syncthreads();

    for (int i = t; i < cnt_here; i += L1_THREADS) {
        unsigned int v = reorder[i];
        unsigned int b = v >> 23;
        buck_arr[(size_t)b * CAP + runb[b] + ((unsigned int)i - lbase[b])] = v;
    }
}

// ---- CSR B: per-bucket fine sort; emits src16 (slab-local), starts/ends/dinv ----
__global__ __launch_bounds__(256) void k_fine(const unsigned int* __restrict__ buck_arr,
                                              const int* __restrict__ bucket_cursor,
                                              int* __restrict__ starts,
                                              int* __restrict__ ends,
                                              float* __restrict__ dinv,
                                              unsigned short* __restrict__ src16,
                                              int n) {
    int b = blockIdx.x;
    int base = b * CAP;
    int m = min(bucket_cursor[b], CAP);
    int node0 = b << 7;
    int nn = min(128, n - node0);
    __shared__ unsigned int cnt[128];
    __shared__ unsigned int lsc[256];
    __shared__ unsigned int lcur[128];
    __shared__ unsigned short srcbuf[CAP];
    int t = threadIdx.x;
    if (t < 128) cnt[t] = 0;
    __syncthreads();
    for (int i = t; i < m; i += 256)
        atomicAdd(&cnt[(buck_arr[base + i] >> 16) - node0], 1u);
    __syncthreads();
    unsigned int v0 = (t < 128) ? cnt[t] : 0;
    lsc[t] = v0;
    __syncthreads();
    #pragma unroll
    for (int off = 1; off < 128; off <<= 1) {
        unsigned int add = (t >= off) ? lsc[t - off] : 0;
        __syncthreads();
        lsc[t] += add;
        __syncthreads();
    }
    if (t < 128) {
        unsigned int ex = lsc[t] - v0;
        lcur[t] = ex;
        if (t < nn) {
            starts[node0 + t] = base + (int)ex;
            ends[node0 + t]   = base + (int)(ex + v0);
            dinv[node0 + t]   = rsqrtf((float)v0);   // deg >= 1 (self-loop)
        }
    }
    __syncthreads();
    for (int i = t; i < m; i += 256) {
        unsigned int v = buck_arr[base + i];
        unsigned int p = atomicAdd(&lcur[(v >> 16) - node0], 1u);
        srcbuf[p] = (unsigned short)(v & 0xffffu);
    }
    __syncthreads();
    for (int i = t; i < m; i += 256)
        src16[base + i] = srcbuf[i];
}

// ---- GEMM: Out[M,128](fp8 e4m3, pre-scaled by dinv[row]) = A @ (Whi+Wlo)
// 128 rows/block, 32 rows/wave per W-fragment load (2:1 MFMA:load). ----
__global__ __launch_bounds__(256) void k_gemm_mfma(const float* __restrict__ Af,
                                                   const unsigned short* __restrict__ Ab,
                                                   const unsigned short* __restrict__ Whi,
                                                   const unsigned short* __restrict__ Wlo,
                                                   const float* __restrict__ dinv,
                                                   unsigned char* __restrict__ Out,
                                                   int M) {
    __shared__ unsigned short As[128 * 136];   // 34 KB
    int tid = threadIdx.x;
    int row0 = blockIdx.x * 128;

    if (Af) {
        for (int c = tid; c < 2048; c += 256) {
            int r = c >> 4, off = c & 15;
            int gr = min(row0 + r, M - 1);
            const float4* p = (const float4*)(Af + (size_t)gr * NF) + off * 2;
            float4 v0 = p[0], v1 = p[1];
            uint4 pk;
            pk.x = pack_bf16_rne(v0.x, v0.y);
            pk.y = pack_bf16_rne(v0.z, v0.w);
            pk.z = pack_bf16_rne(v1.x, v1.y);
            pk.w = pack_bf16_rne(v1.z, v1.w);
            *(uint4*)(&As[r * 136 + off * 8]) = pk;
        }
    } else {
        for (int c = tid; c < 2048; c += 256) {
            int r = c >> 4, off = c & 15;
            int gr = min(row0 + r, M - 1);
            *(uint4*)(&As[r * 136 + off * 8]) = ((const uint4*)(Ab + (size_t)gr * NF))[off];
        }
    }
    __syncthreads();

    int wave = tid >> 6, l = tid & 63;
    int q = l >> 4, c16 = l & 15;
    int wrow0 = wave * 16;

    floatx4 acc[2][8];
    #pragma unroll
    for (int h = 0; h < 2; ++h)
        #pragma unroll
        for (int t = 0; t < 8; ++t) acc[h][t] = (floatx4){0.f, 0.f, 0.f, 0.f};

    #pragma unroll
    for (int s = 0; s < 4; ++s) {
        short8 a0 = *(const short8*)(&As[(wrow0 + c16) * 136 + s * 32 + q * 8]);
        short8 a1 = *(const short8*)(&As[(64 + wrow0 + c16) * 136 + s * 32 + q * 8]);
        #pragma unroll
        for (int t = 0; t < 8; ++t) {
            short8 bh = *(const short8*)(Whi + ((size_t)((s * 8 + t) * 64 + l) * 8));
            short8 bl = *(const short8*)(Wlo + ((size_t)((s * 8 + t) * 64 + l) * 8));
            acc[0][t] = __builtin_amdgcn_mfma_f32_16x16x32_bf16(a0, bh, acc[0][t], 0, 0, 0);
            acc[0][t] = __builtin_amdgcn_mfma_f32_16x16x32_bf16(a0, bl, acc[0][t], 0, 0, 0);
            acc[1][t] = __builtin_amdgcn_mfma_f32_16x16x32_bf16(a1, bh, acc[1][t], 0, 0, 0);
            acc[1][t] = __builtin_amdgcn_mfma_f32_16x16x32_bf16(a1, bl, acc[1][t], 0, 0, 0);
        }
    }

    #pragma unroll
    for (int h = 0; h < 2; ++h) {
        float ds[4];
        #pragma unroll
        for (int i = 0; i < 4; ++i) {
            int gr = row0 + h * 64 + wrow0 + q * 4 + i;
            ds[i] = (gr < M) ? dinv[gr] : 0.f;
        }
        #pragma unroll
        for (int t = 0; t < 8; ++t) {
            #pragma unroll
            for (int i = 0; i < 4; ++i) {
                int gr = row0 + h * 64 + wrow0 + q * 4 + i;
                if (gr < M) {
                    float v = acc[h][t][i] * ds[i];
                    unsigned int pk = __builtin_amdgcn_cvt_pk_fp8_f32(v, v, 0, false);
                    Out[(size_t)gr * NF + t * 16 + c16] = (unsigned char)(pk & 0xffu);
                }
            }
        }
    }
}

// ---- out[i] = relu?( dinv[i] * sum_e h8[src_e] + b ), h8 fp8 pre-scaled.
// R14: feature-split — one pass covers 64 feats (fsel selects half). One wave/node;
// lane = (slot g=l>>4, f=l&15); dword (4 fp8 feats)/lane from a 64B half-row;
// 4 slots x unroll 8 = 32 edges in flight. Per-pass gather working set 3.2MB
// fits the 4MB per-XCD L2. Numerics bit-identical to the unsplit version. ----
__global__ __launch_bounds__(256) void k_agg_fp8(const unsigned char* __restrict__ hs8,
                                                 const int* __restrict__ starts,
                                                 const int* __restrict__ ends,
                                                 const unsigned short* __restrict__ src16,
                                                 const float* __restrict__ dinv,
                                                 const float* __restrict__ bias,
                                                 unsigned short* __restrict__ out,
                                                 int n, int do_relu, int fsel) {
    int wave = threadIdx.x >> 6;
    int lane = threadIdx.x & 63;
    int node = blockIdx.x * 4 + wave;
    if (node >= n) return;
    int g = lane >> 4;
    int f = lane & 15;
    int start = starts[node], end = ends[node];

    const unsigned int* h1 = (const unsigned int*)hs8;   // 32 dwords per 128-feat row
    float acc[4];
    #pragma unroll
    for (int j = 0; j < 4; ++j) acc[j] = 0.f;

    for (int base = start; base < end; base += 32) {
        int   sidx[8];
        float msk[8];
        #pragma unroll
        for (int j = 0; j < 8; ++j) {
            int e = base + g + 4 * j;
            bool v = e < end;
            sidx[j] = (int)src16[v ? e : start];  // masked slots reload a VALID row (no NaN decode)
            msk[j]  = v ? 1.f : 0.f;
        }
        unsigned int rr[8];
        #pragma unroll
        for (int j = 0; j < 8; ++j)
            rr[j] = h1[(size_t)sidx[j] * 32 + fsel * 16 + f];
        #pragma unroll
        for (int j = 0; j < 8; ++j) {
            float m = msk[j];
            floatx2 p0 = __builtin_amdgcn_cvt_pk_f32_fp8(rr[j], false);
            floatx2 p1 = __builtin_amdgcn_cvt_pk_f32_fp8(rr[j], true);
            acc[0] = fmaf(m, p0.x, acc[0]);
            acc[1] = fmaf(m, p0.y, acc[1]);
            acc[2] = fmaf(m, p1.x, acc[2]);
            acc[3] = fmaf(m, p1.y, acc[3]);
        }
    }

    // fold the 4 edge slots (lanes 16 apart hold the same feat group)
    #pragma unroll
    for (int j = 0; j < 4; ++j) {
        acc[j] += __shfl_xor(acc[j], 16);
        acc[j] += __shfl_xor(acc[j], 32);
    }

    if (g == 0) {
        float dd = dinv[node];
        float4 bb = ((const float4*)bias)[fsel * 16 + f];   // feats fsel*64 + f*4 ..+3
        float r[4];
        r[0] = fmaf(dd, acc[0], bb.x); r[1] = fmaf(dd, acc[1], bb.y);
        r[2] = fmaf(dd, acc[2], bb.z); r[3] = fmaf(dd, acc[3], bb.w);
        if (do_relu) {
            #pragma unroll
            for (int j = 0; j < 4; ++j) r[j] = fmaxf(r[j], 0.f);
        }
        uint2 pk;
        pk.x = pack_bf16_rne(r[0], r[1]);
        pk.y = pack_bf16_rne(r[2], r[3]);
        ((uint2*)out)[(size_t)node * 32 + fsel * 16 + f] = pk;
    }
}

// ---- pooling: deterministic partial slabs (no atomics, no memset).
// uint4 loads (16B/lane), 8-row register tile + LDS fold. ----
__global__ __launch_bounds__(128) void k_pool_partial(const unsigned short* __restrict__ h,
                                                      const int* __restrict__ batch,
                                                      float* __restrict__ pooled_part,
                                                      int n) {
    __shared__ float red[8][NF];
    int b = blockIdx.x;
    int g = b / PPG;
    int j = b % PPG;
    int t = threadIdx.x;

    int lo = 0, hi = n;
    while (lo < hi) { int mid = (lo + hi) >> 1; if (batch[mid] < g) lo = mid + 1; else hi = mid; }
    int s = lo;
    lo = s; hi = n;
    while (lo < hi) { int mid = (lo + hi) >> 1; if (batch[mid] < g + 1) lo = mid + 1; else hi = mid; }
    int e = lo;

    int len = e - s;
    int chunk = (len + PPG - 1) / PPG;
    int i0 = s + j * chunk;
    int i1 = min(e, i0 + chunk);

    int r = t >> 4, f8 = t & 15;
    float acc[8];
    #pragma unroll
    for (int k = 0; k < 8; ++k) acc[k] = 0.f;
    for (int i = i0 + r; i < i1; i += 8) {
        uint4 v = *(const uint4*)(&h[(size_t)i * NF + f8 * 8]);
        acc[0] += bf16u_to_f32(v.x & 0xffffu); acc[1] += bf16u_to_f32(v.x >> 16);
        acc[2] += bf16u_to_f32(v.y & 0xffffu); acc[3] += bf16u_to_f32(v.y >> 16);
        acc[4] += bf16u_to_f32(v.z & 0xffffu); acc[5] += bf16u_to_f32(v.z >> 16);
        acc[6] += bf16u_to_f32(v.w & 0xffffu); acc[7] += bf16u_to_f32(v.w >> 16);
    }
    #pragma unroll
    for (int k = 0; k < 8; ++k) red[r][f8 * 8 + k] = acc[k];
    __syncthreads();
    float ssum = 0.f;
    #pragma unroll
    for (int rr = 0; rr < 8; ++rr) ssum += red[rr][t];
    pooled_part[(size_t)b * NF + t] = ssum;
}

// ---- head: fold partials in LDS, counts + linear 128x16 + softmax ----
__global__ __launch_bounds__(1024) void k_head(const float* __restrict__ pooled_part,
                                               const int* __restrict__ batch,
                                               const float* __restrict__ linW,
                                               const float* __restrict__ linb,
                                               float* __restrict__ out,
                                               int n, int n_graphs) {
    __shared__ float ph[64 * NF];  // 32 KB
    int t = threadIdx.x;
    for (int i = t; i < n_graphs * NF; i += 1024) {
        int g = i >> 7, f = i & 127;
        float s = 0.f;
        #pragma unroll
        for (int j = 0; j < PPG; ++j)
            s += pooled_part[(size_t)(g * PPG + j) * NF + f];
        ph[i] = s;
    }
    __syncthreads();

    int g = t >> 4;
    int c = t & 15;

    int lo = 0, hi = n;
    while (lo < hi) { int mid = (lo + hi) >> 1; if (batch[mid] < g) lo = mid + 1; else hi = mid; }
    int start = lo;
    lo = start; hi = n;
    while (lo < hi) { int mid = (lo + hi) >> 1; if (batch[mid] < g + 1) lo = mid + 1; else hi = mid; }
    float inv_cnt = 1.f / fmaxf((float)(lo - start), 1.f);

    float acc = linb[c];
    for (int k = 0; k < NF; ++k)
        acc += ph[g * NF + k] * inv_cnt * linW[k * 16 + c];

    float m = acc;
    #pragma unroll
    for (int s2 = 8; s2 >= 1; s2 >>= 1) m = fmaxf(m, __shfl_xor(m, s2, 16));
    float e = expf(acc - m);
    float ssum = e;
    #pragma unroll
    for (int s2 = 8; s2 >= 1; s2 >>= 1) ssum += __shfl_xor(ssum, s2, 16);
    out[g * 16 + c] = e / ssum;
}

extern "C" void kernel_launch(void* const* d_in, const int* in_sizes, int n_in,
                              void* d_out, int out_size, void* d_ws, size_t ws_size,
                              hipStream_t stream) {
    const float* x    = (const float*)d_in[0];
    const int*   edge = (const int*)d_in[1];
    const int*   batch= (const int*)d_in[2];
    const float* W0   = (const float*)d_in[3];
    const float* b0   = (const float*)d_in[4];
    const float* W1   = (const float*)d_in[5];
    const float* b1   = (const float*)d_in[6];
    const float* W2   = (const float*)d_in[7];
    const float* b2   = (const float*)d_in[8];
    const float* linW = (const float*)d_in[9];
    const float* linb = (const float*)d_in[10];

    int n  = in_sizes[0] / NF;       // 50000
    int ne = in_sizes[1] / 2;        // 800000
    int n_graphs = out_size / 16;    // 64
    const int* row  = edge;
    const int* colv = edge + ne;
    int etot = ne + n;
    int nbuck = (n + 127) >> 7;      // 391

    char* p = (char*)d_ws;
    auto alloc = [&](size_t bytes) { char* r = p; p += (bytes + 255) & ~(size_t)255; return r; };
    int*   bucket_cursor = (int*)alloc((size_t)(MAXBUCK + 1) * 4);
    unsigned int* buck_arr = (unsigned int*)alloc((size_t)MAXBUCK * CAP * 4);
    unsigned short* src16  = (unsigned short*)alloc((size_t)MAXBUCK * CAP * 2);
    int*   starts  = (int*)  alloc((size_t)n * 4);
    int*   ends    = (int*)  alloc((size_t)n * 4);
    float* dinv    = (float*)alloc((size_t)n * 4);
    unsigned char*  gbuf8 = (unsigned char*) alloc((size_t)n * NF);      // fp8 gemm out
    unsigned short* abuf  = (unsigned short*)alloc((size_t)n * NF * 2);  // bf16 agg out
    float* pooled_part = (float*)alloc((size_t)n_graphs * PPG * NF * 4);
    unsigned short* whi = (unsigned short*)alloc((size_t)3 * NF * NF * 2);
    unsigned short* wlo = (unsigned short*)alloc((size_t)3 * NF * NF * 2);

    // repack first (block 0 also zeroes bucket cursors)
    k_repack_w3<<<24, 256, 0, stream>>>(W0, W1, W2, whi, wlo, bucket_cursor);

    // CSR build (slab buckets)
    k_bucket_scatter<<<(etot + L1_CHUNK - 1) / L1_CHUNK, L1_THREADS, 0, stream>>>(
        row, colv, bucket_cursor, buck_arr, ne, etot, nbuck);
    k_fine<<<nbuck, 256, 0, stream>>>(buck_arr, bucket_cursor, starts, ends, dinv, src16, n);

    int gemm_blocks = (n + 127) / 128;
    int agg_blocks  = (n + 3) / 4;
    const size_t WSLAB = (size_t)NF * NF;

    k_gemm_mfma<<<gemm_blocks, 256, 0, stream>>>(x, nullptr, whi, wlo, dinv, gbuf8, n);
    k_agg_fp8  <<<agg_blocks, 256, 0, stream>>>(gbuf8, starts, ends, src16, dinv, b0, abuf, n, 1, 0);
    k_agg_fp8  <<<agg_blocks, 256, 0, stream>>>(gbuf8, starts, ends, src16, dinv, b0, abuf, n, 1, 1);
    k_gemm_mfma<<<gemm_blocks, 256, 0, stream>>>(nullptr, abuf, whi + WSLAB, wlo + WSLAB, dinv, gbuf8, n);
    k_agg_fp8  <<<agg_blocks, 256, 0, stream>>>(gbuf8, starts, ends, src16, dinv, b1, abuf, n, 1, 0);
    k_agg_fp8  <<<agg_blocks, 256, 0, stream>>>(gbuf8, starts, ends, src16, dinv, b1, abuf, n, 1, 1);
    k_gemm_mfma<<<gemm_blocks, 256, 0, stream>>>(nullptr, abuf, whi + 2 * WSLAB, wlo + 2 * WSLAB, dinv, gbuf8, n);
    k_agg_fp8  <<<agg_blocks, 256, 0, stream>>>(gbuf8, starts, ends, src16, dinv, b2, abuf, n, 0, 0);
    k_agg_fp8  <<<agg_blocks, 256, 0, stream>>>(gbuf8, starts, ends, src16, dinv, b2, abuf, n, 0, 1);

    // pool (no atomics/memset) + head
    k_pool_partial<<<n_graphs * PPG, 128, 0, stream>>>(abuf, batch, pooled_part, n);
    k_head<<<1, 1024, 0, stream>>>(pooled_part, batch, linW, linb, (float*)d_out, n, n_graphs);
}

// Round 6
// 277.006 us; speedup vs baseline: 8.8643x; 1.1392x over previous
//
#include <hip/hip_runtime.h>

// GCN: 3x (GEMM 128x128 + normalized scatter-sum) + mean-pool + linear + softmax.
// R1: two-stage pool. R2: parallel scan. R3: bf16 + split-W MFMA GEMM.
// R4: agg multi-edge-in-flight. R5: CSR via two-level bucket sort.
// R6 FAILED (fusion cut gather parallelism). R7/R8: 16/32 edges in flight (neutral ->
// agg latency-hidden). R9: fp8 e4m3 gather payload (292us).
// R10 FAILED (cooperative grid.sync flushed per-XCD L2s: 505MB HBM/dispatch).
// R11: gemm 128-row blocks (2:1 MFMA:W-load), pool uint4, scatter 4096-chunks (277us).
// R12 FAILED (bucket-major LDS-atomic agg: dst-collision RMW serialization, 751us).
// R13 FAILED (layer-3 pool via global f32 atomics: cross-XCD coherence traffic).
// R14 FAILED (feature-split agg 315us: +3 boundaries + 2x per-edge issue work;
//     gather memory system was NOT the limiter -> boundaries/issue are the cost).
// R15: dispatch-count attack, math identical to R11:
//     (a) src-side dinv moved from gemm epilogue into agg's existing slot mask
//         (msk = valid ? dinv[src] : 0) -> gemm0 no longer depends on k_fine;
//     (b) fine+gemm0 merged into one 782-block dispatch (block-range split);
//     (c) pool+head replaced by one 64-block k_head_pool (per-graph row-sum +
//         linear + softmax; kills pooled_part roundtrip and the 1-block head).
//     11 -> 9 dispatches.
// Assumes n <= 65536 (src packed u16), n <= 512*128, bucket load < CAP (8.5σ).

#define NF 128
#define MAXBUCK 512
#define CAP 2560           // slab capacity per bucket (mean 2176, sigma ~45)
#define L1_CHUNK 4096
#define L1_THREADS 512
#define L1_PER_THREAD 8    // L1_CHUNK / L1_THREADS

typedef __attribute__((ext_vector_type(8))) short short8;
typedef __attribute__((ext_vector_type(4))) float floatx4;
typedef __attribute__((ext_vector_type(2))) float floatx2;

__device__ __forceinline__ unsigned int bf16_rne(float x) {
    unsigned int u = __float_as_uint(x);
    return (u + 0x7fffu + ((u >> 16) & 1u)) >> 16;
}
__device__ __forceinline__ unsigned int pack_bf16_rne(float x, float y) {
    return bf16_rne(x) | (bf16_rne(y) << 16);
}
__device__ __forceinline__ float bf16u_to_f32(unsigned int u) {
    return __uint_as_float(u << 16);
}

// ---- repack all 3 W (fp32 [k][n]) into B-fragment-major bf16 hi/lo.
// Block 0 also zeroes the bucket cursors — runs before scatter. ----
__global__ __launch_bounds__(256) void k_repack_w3(const float* __restrict__ W0,
                                                   const float* __restrict__ W1,
                                                   const float* __restrict__ W2,
                                                   unsigned short* __restrict__ whi,
                                                   unsigned short* __restrict__ wlo,
                                                   int* __restrict__ bucket_cursor) {
    if (blockIdx.x == 0) {
        for (int i = threadIdx.x; i <= MAXBUCK; i += 256) bucket_cursor[i] = 0;
    }
    int wsel = blockIdx.x >> 3;
    const float* W = (wsel == 0) ? W0 : (wsel == 1) ? W1 : W2;
    int idx = (blockIdx.x & 7) * 256 + threadIdx.x;  // 0..2047
    int slab = wsel * NF * NF;
    int l = idx & 63;
    int t = (idx >> 6) & 7;
    int s = idx >> 9;
    int kbase = s * 32 + (l >> 4) * 8;
    int nn = t * 16 + (l & 15);
    #pragma unroll
    for (int j = 0; j < 8; ++j) {
        float w = W[(kbase + j) * NF + nn];
        unsigned int h = bf16_rne(w);
        float hf = __uint_as_float(h << 16);
        unsigned int lo = bf16_rne(w - hf);
        whi[slab + idx * 8 + j] = (unsigned short)h;
        wlo[slab + idx * 8 + j] = (unsigned short)lo;
    }
}

// ---- CSR A: bucket-grouped scatter into fixed slabs via LDS reorder ----
__global__ __launch_bounds__(L1_THREADS) void k_bucket_scatter(
        const int* __restrict__ row, const int* __restrict__ colv,
        int* __restrict__ bucket_cursor, unsigned int* __restrict__ buck_arr,
        int ne, int etot, int nbuck) {
    __shared__ unsigned int hist[MAXBUCK];
    __shared__ unsigned int lbase[MAXBUCK];
    __shared__ unsigned int lcur[MAXBUCK];
    __shared__ unsigned int runb[MAXBUCK];
    __shared__ unsigned int sa[MAXBUCK], sb[MAXBUCK];
    __shared__ unsigned int reorder[L1_CHUNK];
    int t = threadIdx.x;
    int e0 = blockIdx.x * L1_CHUNK;
    int cnt_here = min(etot - e0, L1_CHUNK);

    hist[t] = 0;
    __syncthreads();

    unsigned int myv[L1_PER_THREAD];
    #pragma unroll
    for (int j = 0; j < L1_PER_THREAD; ++j) {
        int e = e0 + j * L1_THREADS + t;
        if (e < etot) {
            int s, d;
            if (e < ne) { s = row[e]; d = colv[e]; } else { s = d = e - ne; }
            myv[j] = (unsigned int)s | ((unsigned int)d << 16);
            atomicAdd(&hist[d >> 7], 1u);
        } else myv[j] = 0xffffffffu;
    }
    __syncthreads();

    sa[t] = hist[t];
    __syncthreads();
    unsigned int* pin = sa;
    unsigned int* pout = sb;
    #pragma unroll
    for (int off = 1; off < MAXBUCK; off <<= 1) {
        pout[t] = pin[t] + ((t >= off) ? pin[t - off] : 0);
        __syncthreads();
        unsigned int* tmp = pin; pin = pout; pout = tmp;
    }
    unsigned int ex = pin[t] - hist[t];
    lbase[t] = ex;
    lcur[t]  = ex;
    if (t < nbuck && hist[t] > 0)
        runb[t] = (unsigned int)atomicAdd(&bucket_cursor[t], (int)hist[t]);
    __syncthreads();

    #pragma unroll
    for (int j = 0; j < L1_PER_THREAD; ++j) {
        unsigned int v = myv[j];
        if (v != 0xffffffffu) {
            unsigned int p = atomicAdd(&lcur[v >> 23], 1u);
            reorder[p] = v;
        }
    }
    __syncthreads();

    for (int i = t; i < cnt_here; i += L1_THREADS) {
        unsigned int v = reorder[i];
        unsigned int b = v >> 23;
        buck_arr[(size_t)b * CAP + runb[b] + ((unsigned int)i - lbase[b])] = v;
    }
}

// ---- GEMM tile body (no dinv): Out[128,128] fp8 e4m3 = A @ (Whi+Wlo).
// 128 rows/block, 32 rows/wave per W-fragment load (2:1 MFMA:load). ----
__device__ __forceinline__ void gemm_tile(unsigned short* As,
                                          const float* __restrict__ Af,
                                          const unsigned short* __restrict__ Ab,
                                          const unsigned short* __restrict__ Whi,
                                          const unsigned short* __restrict__ Wlo,
                                          unsigned char* __restrict__ Out,
                                          int M, int tile) {
    int tid = threadIdx.x;
    int row0 = tile * 128;

    if (Af) {
        for (int c = tid; c < 2048; c += 256) {
            int r = c >> 4, off = c & 15;
            int gr = min(row0 + r, M - 1);
            const float4* p = (const float4*)(Af + (size_t)gr * NF) + off * 2;
            float4 v0 = p[0], v1 = p[1];
            uint4 pk;
            pk.x = pack_bf16_rne(v0.x, v0.y);
            pk.y = pack_bf16_rne(v0.z, v0.w);
            pk.z = pack_bf16_rne(v1.x, v1.y);
            pk.w = pack_bf16_rne(v1.z, v1.w);
            *(uint4*)(&As[r * 136 + off * 8]) = pk;
        }
    } else {
        for (int c = tid; c < 2048; c += 256) {
            int r = c >> 4, off = c & 15;
            int gr = min(row0 + r, M - 1);
            *(uint4*)(&As[r * 136 + off * 8]) = ((const uint4*)(Ab + (size_t)gr * NF))[off];
        }
    }
    __syncthreads();

    int wave = tid >> 6, l = tid & 63;
    int q = l >> 4, c16 = l & 15;
    int wrow0 = wave * 16;

    floatx4 acc[2][8];
    #pragma unroll
    for (int h = 0; h < 2; ++h)
        #pragma unroll
        for (int t = 0; t < 8; ++t) acc[h][t] = (floatx4){0.f, 0.f, 0.f, 0.f};

    #pragma unroll
    for (int s = 0; s < 4; ++s) {
        short8 a0 = *(const short8*)(&As[(wrow0 + c16) * 136 + s * 32 + q * 8]);
        short8 a1 = *(const short8*)(&As[(64 + wrow0 + c16) * 136 + s * 32 + q * 8]);
        #pragma unroll
        for (int t = 0; t < 8; ++t) {
            short8 bh = *(const short8*)(Whi + ((size_t)((s * 8 + t) * 64 + l) * 8));
            short8 bl = *(const short8*)(Wlo + ((size_t)((s * 8 + t) * 64 + l) * 8));
            acc[0][t] = __builtin_amdgcn_mfma_f32_16x16x32_bf16(a0, bh, acc[0][t], 0, 0, 0);
            acc[0][t] = __builtin_amdgcn_mfma_f32_16x16x32_bf16(a0, bl, acc[0][t], 0, 0, 0);
            acc[1][t] = __builtin_amdgcn_mfma_f32_16x16x32_bf16(a1, bh, acc[1][t], 0, 0, 0);
            acc[1][t] = __builtin_amdgcn_mfma_f32_16x16x32_bf16(a1, bl, acc[1][t], 0, 0, 0);
        }
    }

    #pragma unroll
    for (int h = 0; h < 2; ++h) {
        #pragma unroll
        for (int t = 0; t < 8; ++t) {
            #pragma unroll
            for (int i = 0; i < 4; ++i) {
                int gr = row0 + h * 64 + wrow0 + q * 4 + i;
                if (gr < M) {
                    float v = acc[h][t][i];
                    unsigned int pk = __builtin_amdgcn_cvt_pk_fp8_f32(v, v, 0, false);
                    Out[(size_t)gr * NF + t * 16 + c16] = (unsigned char)(pk & 0xffu);
                }
            }
        }
    }
}

// ---- merged: blocks [0,nbuck) = CSR fine sort; blocks [nbuck, nbuck+tiles) = gemm0.
// Both depend only on scatter (+repack). gemm needs no dinv (src scale in agg). ----
union FgSmem {
    struct {
        unsigned int cnt[128]; unsigned int lsc[256]; unsigned int lcur[128];
        unsigned short srcbuf[CAP];
    } fi;
    unsigned short As[128 * 136];   // 34816 B dominates
};

__global__ __launch_bounds__(256) void k_fine_gemm0(
        const unsigned int* __restrict__ buck_arr,
        const int* __restrict__ bucket_cursor,
        int* __restrict__ starts, int* __restrict__ ends,
        float* __restrict__ dinv, unsigned short* __restrict__ src16,
        const float* __restrict__ x,
        const unsigned short* __restrict__ Whi, const unsigned short* __restrict__ Wlo,
        unsigned char* __restrict__ gbuf8,
        int n, int nbuck) {
    __shared__ FgSmem sm;
    int t = threadIdx.x;

    if ((int)blockIdx.x >= nbuck) {
        gemm_tile(sm.As, x, nullptr, Whi, Wlo, gbuf8, n, blockIdx.x - nbuck);
        return;
    }

    int b = blockIdx.x;
    int base = b * CAP;
    int m = min(bucket_cursor[b], CAP);
    int node0 = b << 7;
    int nn = min(128, n - node0);
    if (t < 128) sm.fi.cnt[t] = 0;
    __syncthreads();
    for (int i = t; i < m; i += 256)
        atomicAdd(&sm.fi.cnt[(buck_arr[base + i] >> 16) - node0], 1u);
    __syncthreads();
    unsigned int v0 = (t < 128) ? sm.fi.cnt[t] : 0;
    sm.fi.lsc[t] = v0;
    __syncthreads();
    #pragma unroll
    for (int off = 1; off < 128; off <<= 1) {
        unsigned int add = (t >= off) ? sm.fi.lsc[t - off] : 0;
        __syncthreads();
        sm.fi.lsc[t] += add;
        __syncthreads();
    }
    if (t < 128) {
        unsigned int ex = sm.fi.lsc[t] - v0;
        sm.fi.lcur[t] = ex;
        if (t < nn) {
            starts[node0 + t] = base + (int)ex;
            ends[node0 + t]   = base + (int)(ex + v0);
            dinv[node0 + t]   = rsqrtf((float)v0);   // deg >= 1 (self-loop)
        }
    }
    __syncthreads();
    for (int i = t; i < m; i += 256) {
        unsigned int v = buck_arr[base + i];
        unsigned int p = atomicAdd(&sm.fi.lcur[(v >> 16) - node0], 1u);
        sm.fi.srcbuf[p] = (unsigned short)(v & 0xffffu);
    }
    __syncthreads();
    for (int i = t; i < m; i += 256)
        src16[base + i] = sm.fi.srcbuf[i];
}

// ---- standalone gemm (layers 1,2) ----
__global__ __launch_bounds__(256) void k_gemm_mfma(const unsigned short* __restrict__ Ab,
                                                   const unsigned short* __restrict__ Whi,
                                                   const unsigned short* __restrict__ Wlo,
                                                   unsigned char* __restrict__ Out,
                                                   int M) {
    __shared__ unsigned short As[128 * 136];
    gemm_tile(As, nullptr, Ab, Whi, Wlo, Out, M, blockIdx.x);
}

// ---- out[i] = relu?( dinv[i] * sum_e dinv[src_e]*h8[src_e] + b ), h8 fp8 unscaled.
// One wave/node; lane = (slot g=l>>4, feat f=l&15); uint2 (8 fp8 feats)/lane;
// 4 slots x unroll 8 = 32 edges in flight. Slot mask carries dinv[src] (0 if tail). ----
__global__ __launch_bounds__(256) void k_agg_fp8(const unsigned char* __restrict__ hs8,
                                                 const int* __restrict__ starts,
                                                 const int* __restrict__ ends,
                                                 const unsigned short* __restrict__ src16,
                                                 const float* __restrict__ dinv,
                                                 const float* __restrict__ bias,
                                                 unsigned short* __restrict__ out,
                                                 int n, int do_relu) {
    int wave = threadIdx.x >> 6;
    int lane = threadIdx.x & 63;
    int node = blockIdx.x * 4 + wave;
    if (node >= n) return;
    int g = lane >> 4;
    int f = lane & 15;
    int start = starts[node], end = ends[node];

    const uint2* h2 = (const uint2*)hs8;   // 16 uint2 per 128-feat fp8 row
    float acc[8];
    #pragma unroll
    for (int j = 0; j < 8; ++j) acc[j] = 0.f;

    for (int base = start; base < end; base += 32) {
        int   sidx[8];
        float msk[8];
        #pragma unroll
        for (int j = 0; j < 8; ++j) {
            int e = base + g + 4 * j;
            bool v = e < end;
            int si = (int)src16[v ? e : start];  // masked slots reload a VALID row
            sidx[j] = si;
            msk[j]  = v ? dinv[si] : 0.f;        // src-side norm folded into mask
        }
        uint2 rr[8];
        #pragma unroll
        for (int j = 0; j < 8; ++j)
            rr[j] = h2[(size_t)sidx[j] * 16 + f];
        #pragma unroll
        for (int j = 0; j < 8; ++j) {
            float m = msk[j];
            floatx2 p0 = __builtin_amdgcn_cvt_pk_f32_fp8(rr[j].x, false);
            floatx2 p1 = __builtin_amdgcn_cvt_pk_f32_fp8(rr[j].x, true);
            floatx2 p2 = __builtin_amdgcn_cvt_pk_f32_fp8(rr[j].y, false);
            floatx2 p3 = __builtin_amdgcn_cvt_pk_f32_fp8(rr[j].y, true);
            acc[0] = fmaf(m, p0.x, acc[0]);
            acc[1] = fmaf(m, p0.y, acc[1]);
            acc[2] = fmaf(m, p1.x, acc[2]);
            acc[3] = fmaf(m, p1.y, acc[3]);
            acc[4] = fmaf(m, p2.x, acc[4]);
            acc[5] = fmaf(m, p2.y, acc[5]);
            acc[6] = fmaf(m, p3.x, acc[6]);
            acc[7] = fmaf(m, p3.y, acc[7]);
        }
    }

    // fold the 4 edge slots (lanes 16 apart hold the same feat group)
    #pragma unroll
    for (int j = 0; j < 8; ++j) {
        acc[j] += __shfl_xor(acc[j], 16);
        acc[j] += __shfl_xor(acc[j], 32);
    }

    if (g == 0) {
        float dd = dinv[node];
        float4 b0 = ((const float4*)bias)[2 * f];
        float4 b1 = ((const float4*)bias)[2 * f + 1];
        float r[8];
        r[0] = fmaf(dd, acc[0], b0.x); r[1] = fmaf(dd, acc[1], b0.y);
        r[2] = fmaf(dd, acc[2], b0.z); r[3] = fmaf(dd, acc[3], b0.w);
        r[4] = fmaf(dd, acc[4], b1.x); r[5] = fmaf(dd, acc[5], b1.y);
        r[6] = fmaf(dd, acc[6], b1.z); r[7] = fmaf(dd, acc[7], b1.w);
        if (do_relu) {
            #pragma unroll
            for (int j = 0; j < 8; ++j) r[j] = fmaxf(r[j], 0.f);
        }
        uint4 pk;
        pk.x = pack_bf16_rne(r[0], r[1]);
        pk.y = pack_bf16_rne(r[2], r[3]);
        pk.z = pack_bf16_rne(r[4], r[5]);
        pk.w = pack_bf16_rne(r[6], r[7]);
        ((uint4*)out)[(size_t)node * 16 + f] = pk;
    }
}

// ---- head+pool: one block per graph. Row-sum (uint4, 16 rowslots x 16 featgroups)
// -> LDS fold -> 16-lane linear 128x16 + softmax. ----
__global__ __launch_bounds__(256) void k_head_pool(const unsigned short* __restrict__ h,
                                                   const int* __restrict__ batch,
                                                   const float* __restrict__ linW,
                                                   const float* __restrict__ linb,
                                                   float* __restrict__ out,
                                                   int n) {
    __shared__ float red[16][NF];
    __shared__ float ph[NF];
    int g = blockIdx.x;
    int t = threadIdx.x;

    int lo = 0, hi = n;
    while (lo < hi) { int mid = (lo + hi) >> 1; if (batch[mid] < g) lo = mid + 1; else hi = mid; }
    int s = lo;
    lo = s; hi = n;
    while (lo < hi) { int mid = (lo + hi) >> 1; if (batch[mid] < g + 1) lo = mid + 1; else hi = mid; }
    int e = lo;

    int r = t >> 4, f8 = t & 15;
    float acc[8];
    #pragma unroll
    for (int k = 0; k < 8; ++k) acc[k] = 0.f;
    for (int i = s + r; i < e; i += 16) {
        uint4 v = *(const uint4*)(&h[(size_t)i * NF + f8 * 8]);
        acc[0] += bf16u_to_f32(v.x & 0xffffu); acc[1] += bf16u_to_f32(v.x >> 16);
        acc[2] += bf16u_to_f32(v.y & 0xffffu); acc[3] += bf16u_to_f32(v.y >> 16);
        acc[4] += bf16u_to_f32(v.z & 0xffffu); acc[5] += bf16u_to_f32(v.z >> 16);
        acc[6] += bf16u_to_f32(v.w & 0xffffu); acc[7] += bf16u_to_f32(v.w >> 16);
    }
    #pragma unroll
    for (int k = 0; k < 8; ++k) red[r][f8 * 8 + k] = acc[k];
    __syncthreads();
    if (t < NF) {
        float ssum = 0.f;
        #pragma unroll
        for (int rr = 0; rr < 16; ++rr) ssum += red[rr][t];
        ph[t] = ssum;
    }
    __syncthreads();

    if (t < 16) {
        float inv_cnt = 1.f / fmaxf((float)(e - s), 1.f);
        float acc2 = linb[t];
        for (int k = 0; k < NF; ++k)
            acc2 += ph[k] * inv_cnt * linW[k * 16 + t];
        float m = acc2;
        #pragma unroll
        for (int s2 = 8; s2 >= 1; s2 >>= 1) m = fmaxf(m, __shfl_xor(m, s2, 16));
        float ee = expf(acc2 - m);
        float ssum = ee;
        #pragma unroll
        for (int s2 = 8; s2 >= 1; s2 >>= 1) ssum += __shfl_xor(ssum, s2, 16);
        out[g * 16 + t] = ee / ssum;
    }
}

extern "C" void kernel_launch(void* const* d_in, const int* in_sizes, int n_in,
                              void* d_out, int out_size, void* d_ws, size_t ws_size,
                              hipStream_t stream) {
    const float* x    = (const float*)d_in[0];
    const int*   edge = (const int*)d_in[1];
    const int*   batch= (const int*)d_in[2];
    const float* W0   = (const float*)d_in[3];
    const float* b0   = (const float*)d_in[4];
    const float* W1   = (const float*)d_in[5];
    const float* b1   = (const float*)d_in[6];
    const float* W2   = (const float*)d_in[7];
    const float* b2   = (const float*)d_in[8];
    const float* linW = (const float*)d_in[9];
    const float* linb = (const float*)d_in[10];

    int n  = in_sizes[0] / NF;       // 50000
    int ne = in_sizes[1] / 2;        // 800000
    int n_graphs = out_size / 16;    // 64
    const int* row  = edge;
    const int* colv = edge + ne;
    int etot = ne + n;
    int nbuck = (n + 127) >> 7;      // 391

    char* p = (char*)d_ws;
    auto alloc = [&](size_t bytes) { char* r = p; p += (bytes + 255) & ~(size_t)255; return r; };
    int*   bucket_cursor = (int*)alloc((size_t)(MAXBUCK + 1) * 4);
    unsigned int* buck_arr = (unsigned int*)alloc((size_t)MAXBUCK * CAP * 4);
    unsigned short* src16  = (unsigned short*)alloc((size_t)MAXBUCK * CAP * 2);
    int*   starts  = (int*)  alloc((size_t)n * 4);
    int*   ends    = (int*)  alloc((size_t)n * 4);
    float* dinv    = (float*)alloc((size_t)n * 4);
    unsigned char*  gbuf8 = (unsigned char*) alloc((size_t)n * NF);      // fp8 gemm out
    unsigned short* abuf  = (unsigned short*)alloc((size_t)n * NF * 2);  // bf16 agg out
    unsigned short* whi = (unsigned short*)alloc((size_t)3 * NF * NF * 2);
    unsigned short* wlo = (unsigned short*)alloc((size_t)3 * NF * NF * 2);

    // repack first (block 0 also zeroes bucket cursors)
    k_repack_w3<<<24, 256, 0, stream>>>(W0, W1, W2, whi, wlo, bucket_cursor);

    // CSR coarse scatter
    k_bucket_scatter<<<(etot + L1_CHUNK - 1) / L1_CHUNK, L1_THREADS, 0, stream>>>(
        row, colv, bucket_cursor, buck_arr, ne, etot, nbuck);

    int gemm_blocks = (n + 127) / 128;
    int agg_blocks  = (n + 3) / 4;
    const size_t WSLAB = (size_t)NF * NF;

    // fine sort + gemm0 in one dispatch (both depend only on scatter/repack)
    k_fine_gemm0<<<nbuck + gemm_blocks, 256, 0, stream>>>(
        buck_arr, bucket_cursor, starts, ends, dinv, src16,
        x, whi, wlo, gbuf8, n, nbuck);

    k_agg_fp8  <<<agg_blocks, 256, 0, stream>>>(gbuf8, starts, ends, src16, dinv, b0, abuf, n, 1);
    k_gemm_mfma<<<gemm_blocks, 256, 0, stream>>>(abuf, whi + WSLAB, wlo + WSLAB, gbuf8, n);
    k_agg_fp8  <<<agg_blocks, 256, 0, stream>>>(gbuf8, starts, ends, src16, dinv, b1, abuf, n, 1);
    k_gemm_mfma<<<gemm_blocks, 256, 0, stream>>>(abuf, whi + 2 * WSLAB, wlo + 2 * WSLAB, gbuf8, n);
    k_agg_fp8  <<<agg_blocks, 256, 0, stream>>>(gbuf8, starts, ends, src16, dinv, b2, abuf, n, 0);

    // per-graph pool + linear + softmax
    k_head_pool<<<n_graphs, 256, 0, stream>>>(abuf, batch, linW, linb, (float*)d_out, n);
}

// Round 7
// 251.467 us; speedup vs baseline: 9.7646x; 1.1016x over previous
//
#include <hip/hip_runtime.h>

// GCN: 3x (GEMM 128x128 + normalized scatter-sum) + mean-pool + linear + softmax.
// R1: two-stage pool. R2: parallel scan. R3: bf16 + split-W MFMA GEMM.
// R4: agg multi-edge-in-flight. R5: CSR via two-level bucket sort.
// R6 FAILED (fusion cut gather parallelism). R7/R8: 16/32 edges in flight (neutral ->
// agg latency-hidden). R9: fp8 e4m3 gather payload (292us).
// R10 FAILED (cooperative grid.sync flushed per-XCD L2s: 505MB HBM/dispatch).
// R11: gemm 128-row blocks, pool uint4, scatter 4096-chunks (277us).
// R12 FAILED (bucket-major LDS-atomic agg: dst-collision RMW serialization).
// R13 FAILED (global-atomic pool: cross-XCD coherence traffic).
// R14 FAILED (feature-split agg: +2x per-edge issue work; gather mem not limiter).
// R15 NEUTRAL (fine+gemm0 merge, head_pool, src-side dinv: boundary savings real
//     but ~1-2us each AND masked by new per-edge dinv loads in agg inner loop).
//     Cross-round algebra (R12): agg ~= 25us/layer; OV cancels.
// R16: (a) wave-owns-COLUMNS gemm: each wave loads only its 1/4 of W fragments
//     (128KB/block total vs 512KB; 4x less L2 W-traffic, L1-friendly), reads all
//     row-tiles from LDS instead. Same MFMA count/order -> same numerics.
//     (b) restore dinv pre-scale in gemm1/2 epilogue (coalesced) so agg1/2 drop
//     the per-edge random dinv load (template<SRC_SCALED>); agg0 keeps it
//     (gemm0 fused with fine -> dinv not ready).
// Assumes n <= 65536 (src packed u16), n <= 512*128, bucket load < CAP (8.5σ).

#define NF 128
#define MAXBUCK 512
#define CAP 2560           // slab capacity per bucket (mean 2176, sigma ~45)
#define L1_CHUNK 4096
#define L1_THREADS 512
#define L1_PER_THREAD 8    // L1_CHUNK / L1_THREADS

typedef __attribute__((ext_vector_type(8))) short short8;
typedef __attribute__((ext_vector_type(4))) float floatx4;
typedef __attribute__((ext_vector_type(2))) float floatx2;

__device__ __forceinline__ unsigned int bf16_rne(float x) {
    unsigned int u = __float_as_uint(x);
    return (u + 0x7fffu + ((u >> 16) & 1u)) >> 16;
}
__device__ __forceinline__ unsigned int pack_bf16_rne(float x, float y) {
    return bf16_rne(x) | (bf16_rne(y) << 16);
}
__device__ __forceinline__ float bf16u_to_f32(unsigned int u) {
    return __uint_as_float(u << 16);
}

// ---- repack all 3 W (fp32 [k][n]) into B-fragment-major bf16 hi/lo.
// Block 0 also zeroes the bucket cursors — runs before scatter. ----
__global__ __launch_bounds__(256) void k_repack_w3(const float* __restrict__ W0,
                                                   const float* __restrict__ W1,
                                                   const float* __restrict__ W2,
                                                   unsigned short* __restrict__ whi,
                                                   unsigned short* __restrict__ wlo,
                                                   int* __restrict__ bucket_cursor) {
    if (blockIdx.x == 0) {
        for (int i = threadIdx.x; i <= MAXBUCK; i += 256) bucket_cursor[i] = 0;
    }
    int wsel = blockIdx.x >> 3;
    const float* W = (wsel == 0) ? W0 : (wsel == 1) ? W1 : W2;
    int idx = (blockIdx.x & 7) * 256 + threadIdx.x;  // 0..2047
    int slab = wsel * NF * NF;
    int l = idx & 63;
    int t = (idx >> 6) & 7;
    int s = idx >> 9;
    int kbase = s * 32 + (l >> 4) * 8;
    int nn = t * 16 + (l & 15);
    #pragma unroll
    for (int j = 0; j < 8; ++j) {
        float w = W[(kbase + j) * NF + nn];
        unsigned int h = bf16_rne(w);
        float hf = __uint_as_float(h << 16);
        unsigned int lo = bf16_rne(w - hf);
        whi[slab + idx * 8 + j] = (unsigned short)h;
        wlo[slab + idx * 8 + j] = (unsigned short)lo;
    }
}

// ---- CSR A: bucket-grouped scatter into fixed slabs via LDS reorder ----
__global__ __launch_bounds__(L1_THREADS) void k_bucket_scatter(
        const int* __restrict__ row, const int* __restrict__ colv,
        int* __restrict__ bucket_cursor, unsigned int* __restrict__ buck_arr,
        int ne, int etot, int nbuck) {
    __shared__ unsigned int hist[MAXBUCK];
    __shared__ unsigned int lbase[MAXBUCK];
    __shared__ unsigned int lcur[MAXBUCK];
    __shared__ unsigned int runb[MAXBUCK];
    __shared__ unsigned int sa[MAXBUCK], sb[MAXBUCK];
    __shared__ unsigned int reorder[L1_CHUNK];
    int t = threadIdx.x;
    int e0 = blockIdx.x * L1_CHUNK;
    int cnt_here = min(etot - e0, L1_CHUNK);

    hist[t] = 0;
    __syncthreads();

    unsigned int myv[L1_PER_THREAD];
    #pragma unroll
    for (int j = 0; j < L1_PER_THREAD; ++j) {
        int e = e0 + j * L1_THREADS + t;
        if (e < etot) {
            int s, d;
            if (e < ne) { s = row[e]; d = colv[e]; } else { s = d = e - ne; }
            myv[j] = (unsigned int)s | ((unsigned int)d << 16);
            atomicAdd(&hist[d >> 7], 1u);
        } else myv[j] = 0xffffffffu;
    }
    __syncthreads();

    sa[t] = hist[t];
    __syncthreads();
    unsigned int* pin = sa;
    unsigned int* pout = sb;
    #pragma unroll
    for (int off = 1; off < MAXBUCK; off <<= 1) {
        pout[t] = pin[t] + ((t >= off) ? pin[t - off] : 0);
        __syncthreads();
        unsigned int* tmp = pin; pin = pout; pout = tmp;
    }
    unsigned int ex = pin[t] - hist[t];
    lbase[t] = ex;
    lcur[t]  = ex;
    if (t < nbuck && hist[t] > 0)
        runb[t] = (unsigned int)atomicAdd(&bucket_cursor[t], (int)hist[t]);
    __syncthreads();

    #pragma unroll
    for (int j = 0; j < L1_PER_THREAD; ++j) {
        unsigned int v = myv[j];
        if (v != 0xffffffffu) {
            unsigned int p = atomicAdd(&lcur[v >> 23], 1u);
            reorder[p] = v;
        }
    }
    __syncthreads();

    for (int i = t; i < cnt_here; i += L1_THREADS) {
        unsigned int v = reorder[i];
        unsigned int b = v >> 23;
        buck_arr[(size_t)b * CAP + runb[b] + ((unsigned int)i - lbase[b])] = v;
    }
}

// ---- GEMM tile body: Out[128,128] fp8 e4m3 = A @ (Whi+Wlo), opt dinv[row] pre-scale.
// R16: wave w owns output cols [32w, 32w+32): loads only its 4 W fragments per
// s-step (128KB W/block total, was 512KB), reads all 8 row-tiles of A from LDS. ----
__device__ __forceinline__ void gemm_tile(unsigned short* As,
                                          const float* __restrict__ Af,
                                          const unsigned short* __restrict__ Ab,
                                          const unsigned short* __restrict__ Whi,
                                          const unsigned short* __restrict__ Wlo,
                                          const float* __restrict__ dinv,  // null = no pre-scale
                                          unsigned char* __restrict__ Out,
                                          int M, int tile) {
    int tid = threadIdx.x;
    int row0 = tile * 128;

    if (Af) {
        for (int c = tid; c < 2048; c += 256) {
            int r = c >> 4, off = c & 15;
            int gr = min(row0 + r, M - 1);
            const float4* p = (const float4*)(Af + (size_t)gr * NF) + off * 2;
            float4 v0 = p[0], v1 = p[1];
            uint4 pk;
            pk.x = pack_bf16_rne(v0.x, v0.y);
            pk.y = pack_bf16_rne(v0.z, v0.w);
            pk.z = pack_bf16_rne(v1.x, v1.y);
            pk.w = pack_bf16_rne(v1.z, v1.w);
            *(uint4*)(&As[r * 136 + off * 8]) = pk;
        }
    } else {
        for (int c = tid; c < 2048; c += 256) {
            int r = c >> 4, off = c & 15;
            int gr = min(row0 + r, M - 1);
            *(uint4*)(&As[r * 136 + off * 8]) = ((const uint4*)(Ab + (size_t)gr * NF))[off];
        }
    }
    __syncthreads();

    int wave = tid >> 6, l = tid & 63;
    int q = l >> 4, c16 = l & 15;
    int t0 = wave * 2;                 // this wave's two 16-col tiles: t0, t0+1

    floatx4 acc[8][2];
    #pragma unroll
    for (int rt = 0; rt < 8; ++rt) {
        acc[rt][0] = (floatx4){0.f, 0.f, 0.f, 0.f};
        acc[rt][1] = (floatx4){0.f, 0.f, 0.f, 0.f};
    }

    #pragma unroll
    for (int s = 0; s < 4; ++s) {
        short8 bh0 = *(const short8*)(Whi + ((size_t)((s * 8 + t0    ) * 64 + l) * 8));
        short8 bl0 = *(const short8*)(Wlo + ((size_t)((s * 8 + t0    ) * 64 + l) * 8));
        short8 bh1 = *(const short8*)(Whi + ((size_t)((s * 8 + t0 + 1) * 64 + l) * 8));
        short8 bl1 = *(const short8*)(Wlo + ((size_t)((s * 8 + t0 + 1) * 64 + l) * 8));
        #pragma unroll
        for (int rt = 0; rt < 8; ++rt) {
            short8 a = *(const short8*)(&As[(rt * 16 + c16) * 136 + s * 32 + q * 8]);
            acc[rt][0] = __builtin_amdgcn_mfma_f32_16x16x32_bf16(a, bh0, acc[rt][0], 0, 0, 0);
            acc[rt][0] = __builtin_amdgcn_mfma_f32_16x16x32_bf16(a, bl0, acc[rt][0], 0, 0, 0);
            acc[rt][1] = __builtin_amdgcn_mfma_f32_16x16x32_bf16(a, bh1, acc[rt][1], 0, 0, 0);
            acc[rt][1] = __builtin_amdgcn_mfma_f32_16x16x32_bf16(a, bl1, acc[rt][1], 0, 0, 0);
        }
    }

    #pragma unroll
    for (int rt = 0; rt < 8; ++rt) {
        #pragma unroll
        for (int i = 0; i < 4; ++i) {
            int gr = row0 + rt * 16 + q * 4 + i;
            if (gr < M) {
                float ds = dinv ? dinv[gr] : 1.0f;
                #pragma unroll
                for (int t2 = 0; t2 < 2; ++t2) {
                    float v = acc[rt][t2][i] * ds;
                    unsigned int pk = __builtin_amdgcn_cvt_pk_fp8_f32(v, v, 0, false);
                    Out[(size_t)gr * NF + (t0 + t2) * 16 + c16] = (unsigned char)(pk & 0xffu);
                }
            }
        }
    }
}

// ---- merged: blocks [0,nbuck) = CSR fine sort; blocks [nbuck, nbuck+tiles) = gemm0.
// Both depend only on scatter (+repack). gemm0 unscaled (dinv not ready). ----
union FgSmem {
    struct {
        unsigned int cnt[128]; unsigned int lsc[256]; unsigned int lcur[128];
        unsigned short srcbuf[CAP];
    } fi;
    unsigned short As[128 * 136];   // 34816 B dominates
};

__global__ __launch_bounds__(256) void k_fine_gemm0(
        const unsigned int* __restrict__ buck_arr,
        const int* __restrict__ bucket_cursor,
        int* __restrict__ starts, int* __restrict__ ends,
        float* __restrict__ dinv, unsigned short* __restrict__ src16,
        const float* __restrict__ x,
        const unsigned short* __restrict__ Whi, const unsigned short* __restrict__ Wlo,
        unsigned char* __restrict__ gbuf8,
        int n, int nbuck) {
    __shared__ FgSmem sm;
    int t = threadIdx.x;

    if ((int)blockIdx.x >= nbuck) {
        gemm_tile(sm.As, x, nullptr, Whi, Wlo, nullptr, gbuf8, n, blockIdx.x - nbuck);
        return;
    }

    int b = blockIdx.x;
    int base = b * CAP;
    int m = min(bucket_cursor[b], CAP);
    int node0 = b << 7;
    int nn = min(128, n - node0);
    if (t < 128) sm.fi.cnt[t] = 0;
    __syncthreads();
    for (int i = t; i < m; i += 256)
        atomicAdd(&sm.fi.cnt[(buck_arr[base + i] >> 16) - node0], 1u);
    __syncthreads();
    unsigned int v0 = (t < 128) ? sm.fi.cnt[t] : 0;
    sm.fi.lsc[t] = v0;
    __syncthreads();
    #pragma unroll
    for (int off = 1; off < 128; off <<= 1) {
        unsigned int add = (t >= off) ? sm.fi.lsc[t - off] : 0;
        __syncthreads();
        sm.fi.lsc[t] += add;
        __syncthreads();
    }
    if (t < 128) {
        unsigned int ex = sm.fi.lsc[t] - v0;
        sm.fi.lcur[t] = ex;
        if (t < nn) {
            starts[node0 + t] = base + (int)ex;
            ends[node0 + t]   = base + (int)(ex + v0);
            dinv[node0 + t]   = rsqrtf((float)v0);   // deg >= 1 (self-loop)
        }
    }
    __syncthreads();
    for (int i = t; i < m; i += 256) {
        unsigned int v = buck_arr[base + i];
        unsigned int p = atomicAdd(&sm.fi.lcur[(v >> 16) - node0], 1u);
        sm.fi.srcbuf[p] = (unsigned short)(v & 0xffffu);
    }
    __syncthreads();
    for (int i = t; i < m; i += 256)
        src16[base + i] = sm.fi.srcbuf[i];
}

// ---- standalone gemm (layers 1,2): dinv[row] pre-scaled epilogue ----
__global__ __launch_bounds__(256) void k_gemm_mfma(const unsigned short* __restrict__ Ab,
                                                   const unsigned short* __restrict__ Whi,
                                                   const unsigned short* __restrict__ Wlo,
                                                   const float* __restrict__ dinv,
                                                   unsigned char* __restrict__ Out,
                                                   int M) {
    __shared__ unsigned short As[128 * 136];
    gemm_tile(As, nullptr, Ab, Whi, Wlo, dinv, Out, M, blockIdx.x);
}

// ---- out[i] = relu?( dinv[i] * sum_e w_e*h8[src_e] + b ).
// SRC_SCALED: payload pre-scaled by dinv[src] in gemm epilogue -> mask is 1/0.
// else: mask carries dinv[src] (layer 0). One wave/node; 32 edges in flight. ----
template <bool SRC_SCALED>
__global__ __launch_bounds__(256) void k_agg_fp8(const unsigned char* __restrict__ hs8,
                                                 const int* __restrict__ starts,
                                                 const int* __restrict__ ends,
                                                 const unsigned short* __restrict__ src16,
                                                 const float* __restrict__ dinv,
                                                 const float* __restrict__ bias,
                                                 unsigned short* __restrict__ out,
                                                 int n, int do_relu) {
    int wave = threadIdx.x >> 6;
    int lane = threadIdx.x & 63;
    int node = blockIdx.x * 4 + wave;
    if (node >= n) return;
    int g = lane >> 4;
    int f = lane & 15;
    int start = starts[node], end = ends[node];

    const uint2* h2 = (const uint2*)hs8;   // 16 uint2 per 128-feat fp8 row
    float acc[8];
    #pragma unroll
    for (int j = 0; j < 8; ++j) acc[j] = 0.f;

    for (int base = start; base < end; base += 32) {
        int   sidx[8];
        float msk[8];
        #pragma unroll
        for (int j = 0; j < 8; ++j) {
            int e = base + g + 4 * j;
            bool v = e < end;
            int si = (int)src16[v ? e : start];  // masked slots reload a VALID row
            sidx[j] = si;
            if (SRC_SCALED) msk[j] = v ? 1.f : 0.f;
            else            msk[j] = v ? dinv[si] : 0.f;
        }
        uint2 rr[8];
        #pragma unroll
        for (int j = 0; j < 8; ++j)
            rr[j] = h2[(size_t)sidx[j] * 16 + f];
        #pragma unroll
        for (int j = 0; j < 8; ++j) {
            float m = msk[j];
            floatx2 p0 = __builtin_amdgcn_cvt_pk_f32_fp8(rr[j].x, false);
            floatx2 p1 = __builtin_amdgcn_cvt_pk_f32_fp8(rr[j].x, true);
            floatx2 p2 = __builtin_amdgcn_cvt_pk_f32_fp8(rr[j].y, false);
            floatx2 p3 = __builtin_amdgcn_cvt_pk_f32_fp8(rr[j].y, true);
            acc[0] = fmaf(m, p0.x, acc[0]);
            acc[1] = fmaf(m, p0.y, acc[1]);
            acc[2] = fmaf(m, p1.x, acc[2]);
            acc[3] = fmaf(m, p1.y, acc[3]);
            acc[4] = fmaf(m, p2.x, acc[4]);
            acc[5] = fmaf(m, p2.y, acc[5]);
            acc[6] = fmaf(m, p3.x, acc[6]);
            acc[7] = fmaf(m, p3.y, acc[7]);
        }
    }

    // fold the 4 edge slots (lanes 16 apart hold the same feat group)
    #pragma unroll
    for (int j = 0; j < 8; ++j) {
        acc[j] += __shfl_xor(acc[j], 16);
        acc[j] += __shfl_xor(acc[j], 32);
    }

    if (g == 0) {
        float dd = dinv[node];
        float4 b0 = ((const float4*)bias)[2 * f];
        float4 b1 = ((const float4*)bias)[2 * f + 1];
        float r[8];
        r[0] = fmaf(dd, acc[0], b0.x); r[1] = fmaf(dd, acc[1], b0.y);
        r[2] = fmaf(dd, acc[2], b0.z); r[3] = fmaf(dd, acc[3], b0.w);
        r[4] = fmaf(dd, acc[4], b1.x); r[5] = fmaf(dd, acc[5], b1.y);
        r[6] = fmaf(dd, acc[6], b1.z); r[7] = fmaf(dd, acc[7], b1.w);
        if (do_relu) {
            #pragma unroll
            for (int j = 0; j < 8; ++j) r[j] = fmaxf(r[j], 0.f);
        }
        uint4 pk;
        pk.x = pack_bf16_rne(r[0], r[1]);
        pk.y = pack_bf16_rne(r[2], r[3]);
        pk.z = pack_bf16_rne(r[4], r[5]);
        pk.w = pack_bf16_rne(r[6], r[7]);
        ((uint4*)out)[(size_t)node * 16 + f] = pk;
    }
}

// ---- head+pool: one block per graph. Row-sum (uint4, 16 rowslots x 16 featgroups)
// -> LDS fold -> 16-lane linear 128x16 + softmax. ----
__global__ __launch_bounds__(256) void k_head_pool(const unsigned short* __restrict__ h,
                                                   const int* __restrict__ batch,
                                                   const float* __restrict__ linW,
                                                   const float* __restrict__ linb,
                                                   float* __restrict__ out,
                                                   int n) {
    __shared__ float red[16][NF];
    __shared__ float ph[NF];
    int g = blockIdx.x;
    int t = threadIdx.x;

    int lo = 0, hi = n;
    while (lo < hi) { int mid = (lo + hi) >> 1; if (batch[mid] < g) lo = mid + 1; else hi = mid; }
    int s = lo;
    lo = s; hi = n;
    while (lo < hi) { int mid = (lo + hi) >> 1; if (batch[mid] < g + 1) lo = mid + 1; else hi = mid; }
    int e = lo;

    int r = t >> 4, f8 = t & 15;
    float acc[8];
    #pragma unroll
    for (int k = 0; k < 8; ++k) acc[k] = 0.f;
    for (int i = s + r; i < e; i += 16) {
        uint4 v = *(const uint4*)(&h[(size_t)i * NF + f8 * 8]);
        acc[0] += bf16u_to_f32(v.x & 0xffffu); acc[1] += bf16u_to_f32(v.x >> 16);
        acc[2] += bf16u_to_f32(v.y & 0xffffu); acc[3] += bf16u_to_f32(v.y >> 16);
        acc[4] += bf16u_to_f32(v.z & 0xffffu); acc[5] += bf16u_to_f32(v.z >> 16);
        acc[6] += bf16u_to_f32(v.w & 0xffffu); acc[7] += bf16u_to_f32(v.w >> 16);
    }
    #pragma unroll
    for (int k = 0; k < 8; ++k) red[r][f8 * 8 + k] = acc[k];
    __syncthreads();
    if (t < NF) {
        float ssum = 0.f;
        #pragma unroll
        for (int rr = 0; rr < 16; ++rr) ssum += red[rr][t];
        ph[t] = ssum;
    }
    __syncthreads();

    if (t < 16) {
        float inv_cnt = 1.f / fmaxf((float)(e - s), 1.f);
        float acc2 = linb[t];
        for (int k = 0; k < NF; ++k)
            acc2 += ph[k] * inv_cnt * linW[k * 16 + t];
        float m = acc2;
        #pragma unroll
        for (int s2 = 8; s2 >= 1; s2 >>= 1) m = fmaxf(m, __shfl_xor(m, s2, 16));
        float ee = expf(acc2 - m);
        float ssum = ee;
        #pragma unroll
        for (int s2 = 8; s2 >= 1; s2 >>= 1) ssum += __shfl_xor(ssum, s2, 16);
        out[g * 16 + t] = ee / ssum;
    }
}

extern "C" void kernel_launch(void* const* d_in, const int* in_sizes, int n_in,
                              void* d_out, int out_size, void* d_ws, size_t ws_size,
                              hipStream_t stream) {
    const float* x    = (const float*)d_in[0];
    const int*   edge = (const int*)d_in[1];
    const int*   batch= (const int*)d_in[2];
    const float* W0   = (const float*)d_in[3];
    const float* b0   = (const float*)d_in[4];
    const float* W1   = (const float*)d_in[5];
    const float* b1   = (const float*)d_in[6];
    const float* W2   = (const float*)d_in[7];
    const float* b2   = (const float*)d_in[8];
    const float* linW = (const float*)d_in[9];
    const float* linb = (const float*)d_in[10];

    int n  = in_sizes[0] / NF;       // 50000
    int ne = in_sizes[1] / 2;        // 800000
    int n_graphs = out_size / 16;    // 64
    const int* row  = edge;
    const int* colv = edge + ne;
    int etot = ne + n;
    int nbuck = (n + 127) >> 7;      // 391

    char* p = (char*)d_ws;
    auto alloc = [&](size_t bytes) { char* r = p; p += (bytes + 255) & ~(size_t)255; return r; };
    int*   bucket_cursor = (int*)alloc((size_t)(MAXBUCK + 1) * 4);
    unsigned int* buck_arr = (unsigned int*)alloc((size_t)MAXBUCK * CAP * 4);
    unsigned short* src16  = (unsigned short*)alloc((size_t)MAXBUCK * CAP * 2);
    int*   starts  = (int*)  alloc((size_t)n * 4);
    int*   ends    = (int*)  alloc((size_t)n * 4);
    float* dinv    = (float*)alloc((size_t)n * 4);
    unsigned char*  gbuf8 = (unsigned char*) alloc((size_t)n * NF);      // fp8 gemm out
    unsigned short* abuf  = (unsigned short*)alloc((size_t)n * NF * 2);  // bf16 agg out
    unsigned short* whi = (unsigned short*)alloc((size_t)3 * NF * NF * 2);
    unsigned short* wlo = (unsigned short*)alloc((size_t)3 * NF * NF * 2);

    // repack first (block 0 also zeroes bucket cursors)
    k_repack_w3<<<24, 256, 0, stream>>>(W0, W1, W2, whi, wlo, bucket_cursor);

    // CSR coarse scatter
    k_bucket_scatter<<<(etot + L1_CHUNK - 1) / L1_CHUNK, L1_THREADS, 0, stream>>>(
        row, colv, bucket_cursor, buck_arr, ne, etot, nbuck);

    int gemm_blocks = (n + 127) / 128;
    int agg_blocks  = (n + 3) / 4;
    const size_t WSLAB = (size_t)NF * NF;

    // fine sort + gemm0 in one dispatch (both depend only on scatter/repack)
    k_fine_gemm0<<<nbuck + gemm_blocks, 256, 0, stream>>>(
        buck_arr, bucket_cursor, starts, ends, dinv, src16,
        x, whi, wlo, gbuf8, n, nbuck);

    k_agg_fp8<false><<<agg_blocks, 256, 0, stream>>>(gbuf8, starts, ends, src16, dinv, b0, abuf, n, 1);
    k_gemm_mfma<<<gemm_blocks, 256, 0, stream>>>(abuf, whi + WSLAB, wlo + WSLAB, dinv, gbuf8, n);
    k_agg_fp8<true><<<agg_blocks, 256, 0, stream>>>(gbuf8, starts, ends, src16, dinv, b1, abuf, n, 1);
    k_gemm_mfma<<<gemm_blocks, 256, 0, stream>>>(abuf, whi + 2 * WSLAB, wlo + 2 * WSLAB, dinv, gbuf8, n);
    k_agg_fp8<true><<<agg_blocks, 256, 0, stream>>>(gbuf8, starts, ends, src16, dinv, b2, abuf, n, 0);

    // per-graph pool + linear + softmax
    k_head_pool<<<n_graphs, 256, 0, stream>>>(abuf, batch, linW, linb, (float*)d_out, n);
}